// Round 1
// baseline (172.413 us; speedup 1.0000x reference)
//
#include <hip/hip_runtime.h>

typedef __attribute__((ext_vector_type(8))) short short8;
typedef __attribute__((ext_vector_type(4))) float f32x4;

#define NV 100000
#define NTILES 6250  // NV / 16

__device__ __forceinline__ unsigned short f2bf(float f) {
  unsigned u = __float_as_uint(f);
  u += 0x7fffu + ((u >> 16) & 1u);   // round-to-nearest-even
  return (unsigned short)(u >> 16);
}

// K0: Bt[d][k] = bf16(var_w[k*64 + d]);  k = m*64+c, flat var_w is [8][64][64]
__global__ __launch_bounds__(256) void k0_prep_w(const float* __restrict__ var_w,
                                                 unsigned short* __restrict__ Bt) {
  int t = blockIdx.x * 256 + threadIdx.x;
  if (t >= 64 * 512) return;
  int d = t >> 9, k = t & 511;
  Bt[t] = f2bf(var_w[k * 64 + d]);
}

// K1: x_u[v][8] = data[v] @ var_u ; data_bf[v][64] = bf16(data[v])
__global__ __launch_bounds__(256) void k1_prep(const float* __restrict__ data,
                                               const float* __restrict__ var_u,
                                               float* __restrict__ xu,
                                               unsigned short* __restrict__ data_bf) {
  __shared__ float u_lds[512];   // var_u [c][w]
  int tid = threadIdx.x;
  u_lds[tid] = var_u[tid];
  u_lds[tid + 256] = var_u[tid + 256];
  __syncthreads();
  int v = blockIdx.x * 256 + tid;
  if (v >= NV) return;
  const float4* dp = (const float4*)(data + v * 64);
  float acc[8];
#pragma unroll
  for (int w = 0; w < 8; ++w) acc[w] = 0.f;
  uint2* ob = (uint2*)(data_bf + v * 64);
#pragma unroll
  for (int cc = 0; cc < 16; ++cc) {
    float4 d4 = dp[cc];
    int c0 = cc * 4;
#pragma unroll
    for (int w = 0; w < 8; ++w)
      acc[w] += d4.x * u_lds[(c0 + 0) * 8 + w] + d4.y * u_lds[(c0 + 1) * 8 + w]
              + d4.z * u_lds[(c0 + 2) * 8 + w] + d4.w * u_lds[(c0 + 3) * 8 + w];
    uint2 pk;
    pk.x = (unsigned)f2bf(d4.x) | ((unsigned)f2bf(d4.y) << 16);
    pk.y = (unsigned)f2bf(d4.z) | ((unsigned)f2bf(d4.w) << 16);
    ob[cc] = pk;
  }
#pragma unroll
  for (int w = 0; w < 8; ++w) xu[v * 8 + w] = acc[w];
}

// K2: per wave: 16 vertices. Phase B (softmax+aggregate) -> LDS bf16 agg[16][512]
//     Phase C: 16x64 output tile = agg @ Bt^T via mfma_f32_16x16x32_bf16.
__global__ __launch_bounds__(256) void k2_main(const float* __restrict__ xu,
    const unsigned short* __restrict__ data_bf,
    const int* __restrict__ edge_dst,
    const float* __restrict__ edge_vals,
    const unsigned short* __restrict__ Bt,
    const float* __restrict__ var_c,
    const float* __restrict__ var_b,
    float* __restrict__ y) {
  __shared__ char aggmem[4 * 16 * 1024];   // 64 KiB: per wave 16 rows x 1024B (512 bf16)
  int wave = threadIdx.x >> 6;
  int l = threadIdx.x & 63;
  int tile = blockIdx.x * 4 + wave;
  if (tile >= NTILES) return;              // no barriers below -> safe early exit
  int vbase = tile * 16;
  int m = l & 7;        // weight-matrix index (phase B)
  int jj = l >> 3;      // c-oct index (phase B) / edge sub-index (softmax)
  int q4 = l >> 4;      // quarter-wave (MFMA k-chunk)
  float cm = var_c[m];
  char* wbase = aggmem + wave * 16384;

  for (int r = 0; r < 16; ++r) {
    int v = vbase + r;
    float xum = xu[v * 8 + m];
    float qreg[2]; int dstreg[2];
#pragma unroll
    for (int p = 0; p < 2; ++p) {
      int e = v * 16 + jj + 8 * p;         // lane (jj,m) handles edge j=jj+8p, matrix m
      int dst = edge_dst[e];
      dstreg[p] = dst;
      float logit = xum - xu[dst * 8 + m] + cm;   // var_v = -var_u
      float ex = __expf(logit);
      float s = ex;
      s += __shfl_xor(s, 1);               // softmax-sum over the 8 m's
      s += __shfl_xor(s, 2);
      s += __shfl_xor(s, 4);
      qreg[p] = ex * __builtin_amdgcn_rcpf(s) * edge_vals[e];  // fold adjacency val
    }
    float acc[8];
#pragma unroll
    for (int i = 0; i < 8; ++i) acc[i] = 0.f;
#pragma unroll
    for (int j = 0; j < 16; ++j) {
      int p = j >> 3;
      int dst = __shfl(dstreg[p], (j & 7) << 3);
      float qv = __shfl(qreg[p], ((j & 7) << 3) | m);
      uint4 g = *(const uint4*)(data_bf + dst * 64 + jj * 8);   // 8 bf16, one 16B load
      acc[0] += qv * __uint_as_float(g.x << 16);
      acc[1] += qv * __uint_as_float(g.x & 0xffff0000u);
      acc[2] += qv * __uint_as_float(g.y << 16);
      acc[3] += qv * __uint_as_float(g.y & 0xffff0000u);
      acc[4] += qv * __uint_as_float(g.z << 16);
      acc[5] += qv * __uint_as_float(g.z & 0xffff0000u);
      acc[6] += qv * __uint_as_float(g.w << 16);
      acc[7] += qv * __uint_as_float(g.w & 0xffff0000u);
    }
    // pack agg row r: element k = m*64 + jj*8 + i  (byte 2k), XOR-swizzled
    uint4 pk;
    pk.x = (unsigned)f2bf(acc[0]) | ((unsigned)f2bf(acc[1]) << 16);
    pk.y = (unsigned)f2bf(acc[2]) | ((unsigned)f2bf(acc[3]) << 16);
    pk.z = (unsigned)f2bf(acc[4]) | ((unsigned)f2bf(acc[5]) << 16);
    pk.w = (unsigned)f2bf(acc[6]) | ((unsigned)f2bf(acc[7]) << 16);
    int bir = m * 128 + jj * 16;
    int bo = bir ^ ((bir >> 3) & 0x70) ^ ((r & 7) << 4);
    *(uint4*)(wbase + r * 1024 + bo) = pk;
  }

  // Phase C: wave-synchronous (same-wave LDS deps; compiler inserts lgkmcnt)
  f32x4 C[4];
#pragma unroll
  for (int nt = 0; nt < 4; ++nt) C[nt] = {0.f, 0.f, 0.f, 0.f};
  int row = l & 15;
#pragma unroll
  for (int ks = 0; ks < 16; ++ks) {
    int bir = ks * 64 + q4 * 16;
    int bo = bir ^ ((bir >> 3) & 0x70) ^ ((row & 7) << 4);
    short8 afrag = *(const short8*)(wbase + row * 1024 + bo);   // A[row][ks*32+q4*8 ..+8]
#pragma unroll
    for (int nt = 0; nt < 4; ++nt) {
      int col = row + nt * 16;
      short8 bfrag = *(const short8*)(Bt + (col * 512 + ks * 32 + q4 * 8));
      C[nt] = __builtin_amdgcn_mfma_f32_16x16x32_bf16(afrag, bfrag, C[nt], 0, 0, 0);
    }
  }
#pragma unroll
  for (int nt = 0; nt < 4; ++nt) {
    int col = row + nt * 16;
    float bias = var_b[col];
#pragma unroll
    for (int i = 0; i < 4; ++i) {
      y[(vbase + q4 * 4 + i) * 64 + col] = C[nt][i] + bias;   // C/D: col=l&15, row=q4*4+i
    }
  }
}

extern "C" void kernel_launch(void* const* d_in, const int* in_sizes, int n_in,
                              void* d_out, int out_size, void* d_ws, size_t ws_size,
                              hipStream_t stream) {
  const float* data      = (const float*)d_in[0];
  // d_in[1] = edge_src: structurally repeat(arange(V),16) -> implicit, unused
  const int*   edge_dst  = (const int*)d_in[2];
  const float* edge_vals = (const float*)d_in[3];
  const float* var_u     = (const float*)d_in[4];
  const float* var_c     = (const float*)d_in[5];
  const float* var_w     = (const float*)d_in[6];
  const float* var_b     = (const float*)d_in[7];
  float* y = (float*)d_out;

  char* ws = (char*)d_ws;
  float*          xu      = (float*)ws;                         // 3,200,000 B
  unsigned short* data_bf = (unsigned short*)(ws + 3200000);    // 12,800,000 B
  unsigned short* Bt      = (unsigned short*)(ws + 16000000);   // 65,536 B

  hipLaunchKernelGGL(k0_prep_w, dim3(128), dim3(256), 0, stream, var_w, Bt);
  hipLaunchKernelGGL(k1_prep, dim3((NV + 255) / 256), dim3(256), 0, stream,
                     data, var_u, xu, data_bf);
  hipLaunchKernelGGL(k2_main, dim3((NTILES + 3) / 4), dim3(256), 0, stream,
                     xu, data_bf, edge_dst, edge_vals, Bt, var_c, var_b, y);
}

// Round 3
// 148.716 us; speedup vs baseline: 1.1593x; 1.1593x over previous
//
#include <hip/hip_runtime.h>

typedef _Float16 half2_t __attribute__((ext_vector_type(2)));
typedef _Float16 half8_t __attribute__((ext_vector_type(8)));
typedef __attribute__((ext_vector_type(4))) float f32x4;

#define NV 100000
#define NTILES 6250  // NV / 16

__device__ __forceinline__ unsigned cvt_pk_u(float a, float b) {
  auto h = __builtin_amdgcn_cvt_pkrtz(a, b);   // __fp16 x2
  return __builtin_bit_cast(unsigned, h);
}
__device__ __forceinline__ half2_t u2h(unsigned u) { return __builtin_bit_cast(half2_t, u); }

__device__ __forceinline__ float dot2h(unsigned x2, unsigned q2, float c) {
#if __has_builtin(__builtin_amdgcn_fdot2)
  return __builtin_amdgcn_fdot2(u2h(x2), u2h(q2), c, false);
#else
  half2_t x = u2h(x2), q = u2h(q2);
  return c + (float)x[0] * (float)q[0] + (float)x[1] * (float)q[1];
#endif
}

// K0: Bt[d][k] = fp16(var_w[k*64 + d]);  k = m*64+c, flat var_w is [8][64][64]
__global__ __launch_bounds__(256) void k0_prep_w(const float* __restrict__ var_w,
                                                 unsigned short* __restrict__ Bt) {
  int t = blockIdx.x * 256 + threadIdx.x;
  if (t >= 64 * 512) return;
  int d = t >> 9, k = t & 511;
  _Float16 h = (_Float16)var_w[k * 64 + d];
  Bt[t] = __builtin_bit_cast(unsigned short, h);
}

// K1: x_u[v][8] = data[v] @ var_u ; data_h[v][64] = fp16(data[v])
__global__ __launch_bounds__(256) void k1_prep(const float* __restrict__ data,
                                               const float* __restrict__ var_u,
                                               float* __restrict__ xu,
                                               unsigned short* __restrict__ data_h) {
  __shared__ float u_lds[512];   // var_u [c][w]
  int tid = threadIdx.x;
  u_lds[tid] = var_u[tid];
  u_lds[tid + 256] = var_u[tid + 256];
  __syncthreads();
  int v = blockIdx.x * 256 + tid;
  if (v >= NV) return;
  const float4* dp = (const float4*)(data + v * 64);
  float acc[8];
#pragma unroll
  for (int w = 0; w < 8; ++w) acc[w] = 0.f;
  uint2* ob = (uint2*)(data_h + v * 64);
#pragma unroll
  for (int cc = 0; cc < 16; ++cc) {
    float4 d4 = dp[cc];
    int c0 = cc * 4;
#pragma unroll
    for (int w = 0; w < 8; ++w)
      acc[w] += d4.x * u_lds[(c0 + 0) * 8 + w] + d4.y * u_lds[(c0 + 1) * 8 + w]
              + d4.z * u_lds[(c0 + 2) * 8 + w] + d4.w * u_lds[(c0 + 3) * 8 + w];
    uint2 pk;
    pk.x = cvt_pk_u(d4.x, d4.y);
    pk.y = cvt_pk_u(d4.z, d4.w);
    ob[cc] = pk;
  }
#pragma unroll
  for (int w = 0; w < 8; ++w) xu[v * 8 + w] = acc[w];
}

// K2: per wave: 16 vertices. Phase B (softmax+aggregate, fp16 dot2, pipelined
// gathers) -> LDS fp16 agg[16][512]. Phase C: 16x64 tile via mfma_f32_16x16x32_f16.
__global__ __launch_bounds__(256) void k2_main(const float* __restrict__ xu,
    const unsigned short* __restrict__ data_h,
    const int* __restrict__ edge_dst,
    const float* __restrict__ edge_vals,
    const unsigned short* __restrict__ Bt,
    const float* __restrict__ var_c,
    const float* __restrict__ var_b,
    float* __restrict__ y) {
  __shared__ __align__(16) char aggmem[4 * 16 * 1024];  // 64 KiB: wave x 16 rows x 1024B
  int wave = threadIdx.x >> 6;
  int l = threadIdx.x & 63;
  int tile = blockIdx.x * 4 + wave;
  if (tile >= NTILES) return;              // no barriers below -> safe early exit
  int vbase = tile * 16;
  int m = l & 7;        // weight-matrix index (phase B)
  int jj = l >> 3;      // c-oct index / edge sub-index (phase B)
  int q4 = l >> 4;      // quarter-wave (MFMA k-chunk)
  float cm = var_c[m];
  char* wbase = aggmem + wave * 16384;

  // ---- software-pipelined phase B ----
  // stage "cur": ready for softmax; stage "nxt": dst/ev/xum loaded, xud in flight
  int dstC[2], dstN[2];
  float evC[2], evN[2], xudC[2], xumC, xumN;
#pragma unroll
  for (int p = 0; p < 2; ++p) {
    int e0 = (vbase + 0) * 16 + jj + 8 * p;
    int e1 = (vbase + 1) * 16 + jj + 8 * p;
    dstC[p] = edge_dst[e0];  evC[p] = edge_vals[e0];
    dstN[p] = edge_dst[e1];  evN[p] = edge_vals[e1];
  }
  xumC = xu[(vbase + 0) * 8 + m];
  xumN = xu[(vbase + 1) * 8 + m];
#pragma unroll
  for (int p = 0; p < 2; ++p) xudC[p] = xu[dstC[p] * 8 + m];

#pragma unroll
  for (int r = 0; r < 16; ++r) {
    // 1. softmax math for vertex r (all inputs resident)
    float q01[2];
#pragma unroll
    for (int p = 0; p < 2; ++p) {
      float ex = __expf(xumC - xudC[p] + cm);
      float s = ex;
      s += __shfl_xor(s, 1);
      s += __shfl_xor(s, 2);
      s += __shfl_xor(s, 4);
      q01[p] = ex * __builtin_amdgcn_rcpf(s) * evC[p];
    }
    unsigned q2u = cvt_pk_u(q01[0], q01[1]);

    // 2. issue future-stage loads (hidden under this vertex's sweep)
    float xudN[2];
    int dstF[2]; float evF[2], xumF;
    if (r + 1 < 16) {
#pragma unroll
      for (int p = 0; p < 2; ++p) xudN[p] = xu[dstN[p] * 8 + m];
    }
    if (r + 2 < 16) {
#pragma unroll
      for (int p = 0; p < 2; ++p) {
        int e = (vbase + r + 2) * 16 + jj + 8 * p;
        dstF[p] = edge_dst[e];  evF[p] = edge_vals[e];
      }
      xumF = xu[(vbase + r + 2) * 8 + m];
    }

    // 3. broadcast dst/q, batch-issue all 16 gathers
    int dstj[16];
#pragma unroll
    for (int j = 0; j < 16; ++j) dstj[j] = __shfl(dstC[j >> 3], (j & 7) << 3);
    unsigned qj2[8];
#pragma unroll
    for (int jq = 0; jq < 8; ++jq) qj2[jq] = __shfl((int)q2u, (jq << 3) | m);
    uint4 g[16];
#pragma unroll
    for (int j = 0; j < 16; ++j)
      g[j] = *(const uint4*)(data_h + dstj[j] * 64 + jj * 8);

    // 4. dot2 sweep: pair edges (jq, jq+8) -> 2 MACs per v_dot2_f32_f16
    float acc[8];
#pragma unroll
    for (int i = 0; i < 8; ++i) acc[i] = 0.f;
#pragma unroll
    for (int jq = 0; jq < 8; ++jq) {
      uint4 A = g[jq], B = g[jq + 8];
      unsigned q2 = qj2[jq];
      acc[0] = dot2h((A.x & 0xffffu) | (B.x << 16), q2, acc[0]);
      acc[1] = dot2h((A.x >> 16) | (B.x & 0xffff0000u), q2, acc[1]);
      acc[2] = dot2h((A.y & 0xffffu) | (B.y << 16), q2, acc[2]);
      acc[3] = dot2h((A.y >> 16) | (B.y & 0xffff0000u), q2, acc[3]);
      acc[4] = dot2h((A.z & 0xffffu) | (B.z << 16), q2, acc[4]);
      acc[5] = dot2h((A.z >> 16) | (B.z & 0xffff0000u), q2, acc[5]);
      acc[6] = dot2h((A.w & 0xffffu) | (B.w << 16), q2, acc[6]);
      acc[7] = dot2h((A.w >> 16) | (B.w & 0xffff0000u), q2, acc[7]);
    }

    // 5. pack agg row r: element k = m*64 + jj*8 + i (byte 2k), XOR-swizzled
    uint4 pk;
    pk.x = cvt_pk_u(acc[0], acc[1]);
    pk.y = cvt_pk_u(acc[2], acc[3]);
    pk.z = cvt_pk_u(acc[4], acc[5]);
    pk.w = cvt_pk_u(acc[6], acc[7]);
    int bir = m * 128 + jj * 16;
    int bo = bir ^ ((bir >> 3) & 0x70) ^ ((r & 7) << 4);
    *(uint4*)(wbase + r * 1024 + bo) = pk;

    // 6. rotate pipeline stages
#pragma unroll
    for (int p = 0; p < 2; ++p) {
      dstC[p] = dstN[p]; evC[p] = evN[p]; xudC[p] = xudN[p];
      dstN[p] = dstF[p]; evN[p] = evF[p];
    }
    xumC = xumN; xumN = xumF;
  }

  // ---- phase C: wave-synchronous MFMA (same-wave LDS deps) ----
  f32x4 C[4];
#pragma unroll
  for (int nt = 0; nt < 4; ++nt) C[nt] = {0.f, 0.f, 0.f, 0.f};
  int row = l & 15;
#pragma unroll
  for (int ks = 0; ks < 16; ++ks) {
    int bir = ks * 64 + q4 * 16;
    int bo = bir ^ ((bir >> 3) & 0x70) ^ ((row & 7) << 4);
    half8_t afrag = *(const half8_t*)(wbase + row * 1024 + bo);  // A[row][ks*32+q4*8..+8]
#pragma unroll
    for (int nt = 0; nt < 4; ++nt) {
      int col = row + nt * 16;
      half8_t bfrag = *(const half8_t*)(Bt + (col * 512 + ks * 32 + q4 * 8));
      C[nt] = __builtin_amdgcn_mfma_f32_16x16x32_f16(afrag, bfrag, C[nt], 0, 0, 0);
    }
  }
#pragma unroll
  for (int nt = 0; nt < 4; ++nt) {
    int col = row + nt * 16;
    float bias = var_b[col];
#pragma unroll
    for (int i = 0; i < 4; ++i) {
      y[(vbase + q4 * 4 + i) * 64 + col] = C[nt][i] + bias;  // C/D: col=l&15, row=q4*4+i
    }
  }
}

extern "C" void kernel_launch(void* const* d_in, const int* in_sizes, int n_in,
                              void* d_out, int out_size, void* d_ws, size_t ws_size,
                              hipStream_t stream) {
  const float* data      = (const float*)d_in[0];
  // d_in[1] = edge_src: structurally repeat(arange(V),16) -> implicit, unused
  const int*   edge_dst  = (const int*)d_in[2];
  const float* edge_vals = (const float*)d_in[3];
  const float* var_u     = (const float*)d_in[4];
  const float* var_c     = (const float*)d_in[5];
  const float* var_w     = (const float*)d_in[6];
  const float* var_b     = (const float*)d_in[7];
  float* y = (float*)d_out;

  char* ws = (char*)d_ws;
  float*          xu     = (float*)ws;                          // 3,200,000 B
  unsigned short* data_h = (unsigned short*)(ws + 3200000);     // 12,800,000 B
  unsigned short* Bt     = (unsigned short*)(ws + 16000000);    // 65,536 B

  hipLaunchKernelGGL(k0_prep_w, dim3(128), dim3(256), 0, stream, var_w, Bt);
  hipLaunchKernelGGL(k1_prep, dim3((NV + 255) / 256), dim3(256), 0, stream,
                     data, var_u, xu, data_h);
  hipLaunchKernelGGL(k2_main, dim3((NTILES + 3) / 4), dim3(256), 0, stream,
                     xu, data_h, edge_dst, edge_vals, Bt, var_c, var_b, y);
}

// Round 4
// 128.164 us; speedup vs baseline: 1.3453x; 1.1604x over previous
//
#include <hip/hip_runtime.h>

typedef _Float16 half2_t __attribute__((ext_vector_type(2)));
typedef _Float16 half8_t __attribute__((ext_vector_type(8)));
typedef __attribute__((ext_vector_type(4))) float f32x4;

#define NV 100000
#define NBLOCKS 3125   // NV / (2 tiles * 16 vertices)

__device__ __forceinline__ unsigned cvt_pk_u(float a, float b) {
  auto h = __builtin_amdgcn_cvt_pkrtz(a, b);   // __fp16 x2
  return __builtin_bit_cast(unsigned, h);
}
__device__ __forceinline__ half2_t u2h(unsigned u) { return __builtin_bit_cast(half2_t, u); }

__device__ __forceinline__ float dot2h(unsigned x2, unsigned q2, float c) {
#if __has_builtin(__builtin_amdgcn_fdot2)
  return __builtin_amdgcn_fdot2(u2h(x2), u2h(q2), c, false);
#else
  half2_t x = u2h(x2), q = u2h(q2);
  return c + (float)x[0] * (float)q[0] + (float)x[1] * (float)q[1];
#endif
}
// pair fp16 halves of A,B: lo = [A.h0, B.h0], hi = [A.h1, B.h1]
__device__ __forceinline__ unsigned perm_lo(unsigned A, unsigned B) {
  return __builtin_amdgcn_perm(B, A, 0x05040100u);   // (A&0xffff)|(B<<16)
}
__device__ __forceinline__ unsigned perm_hi(unsigned A, unsigned B) {
  return __builtin_amdgcn_perm(B, A, 0x07060302u);   // (A>>16)|(B&0xffff0000)
}

// K0: Bt[d][k] = fp16(var_w[k*64 + d]);  k = m*64+c, flat var_w is [8][64][64]
__global__ __launch_bounds__(256) void k0_prep_w(const float* __restrict__ var_w,
                                                 unsigned short* __restrict__ Bt) {
  int t = blockIdx.x * 256 + threadIdx.x;
  if (t >= 64 * 512) return;
  int d = t >> 9, k = t & 511;
  _Float16 h = (_Float16)var_w[k * 64 + d];
  Bt[t] = __builtin_bit_cast(unsigned short, h);
}

// K1: x_u[v][8] = data[v] @ var_u ; data_h[v][64] = fp16(data[v])
__global__ __launch_bounds__(256) void k1_prep(const float* __restrict__ data,
                                               const float* __restrict__ var_u,
                                               float* __restrict__ xu,
                                               unsigned short* __restrict__ data_h) {
  __shared__ float u_lds[512];   // var_u [c][w]
  int tid = threadIdx.x;
  u_lds[tid] = var_u[tid];
  u_lds[tid + 256] = var_u[tid + 256];
  __syncthreads();
  int v = blockIdx.x * 256 + tid;
  if (v >= NV) return;
  const float4* dp = (const float4*)(data + v * 64);
  float acc[8];
#pragma unroll
  for (int w = 0; w < 8; ++w) acc[w] = 0.f;
  uint2* ob = (uint2*)(data_h + v * 64);
#pragma unroll
  for (int cc = 0; cc < 16; ++cc) {
    float4 d4 = dp[cc];
    int c0 = cc * 4;
#pragma unroll
    for (int w = 0; w < 8; ++w)
      acc[w] += d4.x * u_lds[(c0 + 0) * 8 + w] + d4.y * u_lds[(c0 + 1) * 8 + w]
              + d4.z * u_lds[(c0 + 2) * 8 + w] + d4.w * u_lds[(c0 + 3) * 8 + w];
    uint2 pk;
    pk.x = cvt_pk_u(d4.x, d4.y);
    pk.y = cvt_pk_u(d4.z, d4.w);
    ob[cc] = pk;
  }
#pragma unroll
  for (int w = 0; w < 8; ++w) xu[v * 8 + w] = acc[w];
}

// K2: 2 waves cooperate on one 16-vertex tile (w0: rows 0-7, w1: rows 8-15)
// -> 16 KiB LDS per tile, 32 KiB per 256-thr block -> 5 blocks/CU.
// Phase B: softmax+aggregate (fp16 dot2, pipelined gathers) -> LDS agg[16][512].
// Phase C: 16x64 tile via mfma_f32_16x16x32_f16, column-split across the 2 waves.
__global__ __launch_bounds__(256) void k2_main(const float* __restrict__ xu,
    const unsigned short* __restrict__ data_h,
    const int* __restrict__ edge_dst,
    const float* __restrict__ edge_vals,
    const unsigned short* __restrict__ Bt,
    const float* __restrict__ var_c,
    const float* __restrict__ var_b,
    float* __restrict__ y) {
  __shared__ __align__(16) char aggmem[2 * 16 * 1024];  // 32 KiB: 2 tiles x 16 rows x 1024B
  int tid = threadIdx.x;
  int wave = tid >> 6;
  int grp = wave >> 1;       // tile within block
  int wsub = wave & 1;       // row-half within tile
  int l = tid & 63;
  int tile = blockIdx.x * 2 + grp;
  int vbase = tile * 16;
  int rbase = wsub * 8;
  int m = l & 7;        // weight-matrix index (phase B)
  int jj = l >> 3;      // c-oct index / edge sub-index (phase B)
  int q4 = l >> 4;      // quarter-wave (MFMA k-chunk)
  float cm = var_c[m];
  char* gbase = aggmem + grp * 16384;

  // ---- software-pipelined phase B: 8 rows per wave ----
  int dstC[2], dstN[2];
  float evC[2], evN[2], xudC[2], xumC, xumN;
#pragma unroll
  for (int p = 0; p < 2; ++p) {
    int e0 = (vbase + rbase + 0) * 16 + jj + 8 * p;
    int e1 = (vbase + rbase + 1) * 16 + jj + 8 * p;
    dstC[p] = edge_dst[e0];  evC[p] = edge_vals[e0];
    dstN[p] = edge_dst[e1];  evN[p] = edge_vals[e1];
  }
  xumC = xu[(vbase + rbase + 0) * 8 + m];
  xumN = xu[(vbase + rbase + 1) * 8 + m];
#pragma unroll
  for (int p = 0; p < 2; ++p) xudC[p] = xu[dstC[p] * 8 + m];

#pragma unroll
  for (int rr = 0; rr < 8; ++rr) {
    int r = rbase + rr;
    // 1. softmax math for vertex r (all inputs resident)
    float q01[2];
#pragma unroll
    for (int p = 0; p < 2; ++p) {
      float ex = __expf(xumC - xudC[p] + cm);
      float s = ex;
      s += __shfl_xor(s, 1);
      s += __shfl_xor(s, 2);
      s += __shfl_xor(s, 4);
      q01[p] = ex * __builtin_amdgcn_rcpf(s) * evC[p];
    }
    unsigned q2u = cvt_pk_u(q01[0], q01[1]);

    // 2. issue future-stage loads (hidden under this vertex's sweep)
    float xudN[2];
    int dstF[2]; float evF[2], xumF;
    if (rr + 1 < 8) {
#pragma unroll
      for (int p = 0; p < 2; ++p) xudN[p] = xu[dstN[p] * 8 + m];
    }
    if (rr + 2 < 8) {
#pragma unroll
      for (int p = 0; p < 2; ++p) {
        int e = (vbase + r + 2) * 16 + jj + 8 * p;
        dstF[p] = edge_dst[e];  evF[p] = edge_vals[e];
      }
      xumF = xu[(vbase + r + 2) * 8 + m];
    }

    // 3. broadcast dst/q, batch-issue all 16 gathers
    int dstj[16];
#pragma unroll
    for (int j = 0; j < 16; ++j) dstj[j] = __shfl(dstC[j >> 3], (j & 7) << 3);
    unsigned qj2[8];
#pragma unroll
    for (int jq = 0; jq < 8; ++jq) qj2[jq] = __shfl((int)q2u, (jq << 3) | m);
    uint4 g[16];
#pragma unroll
    for (int j = 0; j < 16; ++j)
      g[j] = *(const uint4*)(data_h + dstj[j] * 64 + jj * 8);

    // 4. dot2 sweep: pair edges (jq, jq+8) -> 2 MACs per v_dot2_f32_f16
    float acc[8];
#pragma unroll
    for (int i = 0; i < 8; ++i) acc[i] = 0.f;
#pragma unroll
    for (int jq = 0; jq < 8; ++jq) {
      uint4 A = g[jq], B = g[jq + 8];
      unsigned q2 = qj2[jq];
      acc[0] = dot2h(perm_lo(A.x, B.x), q2, acc[0]);
      acc[1] = dot2h(perm_hi(A.x, B.x), q2, acc[1]);
      acc[2] = dot2h(perm_lo(A.y, B.y), q2, acc[2]);
      acc[3] = dot2h(perm_hi(A.y, B.y), q2, acc[3]);
      acc[4] = dot2h(perm_lo(A.z, B.z), q2, acc[4]);
      acc[5] = dot2h(perm_hi(A.z, B.z), q2, acc[5]);
      acc[6] = dot2h(perm_lo(A.w, B.w), q2, acc[6]);
      acc[7] = dot2h(perm_hi(A.w, B.w), q2, acc[7]);
    }

    // 5. pack agg row r: element k = m*64 + jj*8 + i (byte 2k), XOR-swizzled
    uint4 pk;
    pk.x = cvt_pk_u(acc[0], acc[1]);
    pk.y = cvt_pk_u(acc[2], acc[3]);
    pk.z = cvt_pk_u(acc[4], acc[5]);
    pk.w = cvt_pk_u(acc[6], acc[7]);
    int bir = m * 128 + jj * 16;
    int bo = bir ^ ((bir >> 3) & 0x70) ^ ((r & 7) << 4);
    *(uint4*)(gbase + r * 1024 + bo) = pk;

    // 6. rotate pipeline stages
#pragma unroll
    for (int p = 0; p < 2; ++p) {
      dstC[p] = dstN[p]; evC[p] = evN[p]; xudC[p] = xudN[p];
      dstN[p] = dstF[p]; evN[p] = evF[p];
    }
    xumC = xumN; xumN = xumF;
  }

  __syncthreads();   // tile's 16 rows complete (both waves)

  // ---- phase C: 16x64 tile, column-split across the 2 waves ----
  f32x4 C[2];
#pragma unroll
  for (int ntl = 0; ntl < 2; ++ntl) C[ntl] = {0.f, 0.f, 0.f, 0.f};
  int row = l & 15;
#pragma unroll
  for (int ks = 0; ks < 16; ++ks) {
    int bir = ks * 64 + q4 * 16;
    int bo = bir ^ ((bir >> 3) & 0x70) ^ ((row & 7) << 4);
    half8_t afrag = *(const half8_t*)(gbase + row * 1024 + bo);  // A[row][ks*32+q4*8..+8]
#pragma unroll
    for (int ntl = 0; ntl < 2; ++ntl) {
      int col = row + (wsub * 2 + ntl) * 16;
      half8_t bfrag = *(const half8_t*)(Bt + (col * 512 + ks * 32 + q4 * 8));
      C[ntl] = __builtin_amdgcn_mfma_f32_16x16x32_f16(afrag, bfrag, C[ntl], 0, 0, 0);
    }
  }
#pragma unroll
  for (int ntl = 0; ntl < 2; ++ntl) {
    int col = row + (wsub * 2 + ntl) * 16;
    float bias = var_b[col];
#pragma unroll
    for (int i = 0; i < 4; ++i) {
      y[(vbase + q4 * 4 + i) * 64 + col] = C[ntl][i] + bias;  // C/D: col=l&15, row=q4*4+i
    }
  }
}

extern "C" void kernel_launch(void* const* d_in, const int* in_sizes, int n_in,
                              void* d_out, int out_size, void* d_ws, size_t ws_size,
                              hipStream_t stream) {
  const float* data      = (const float*)d_in[0];
  // d_in[1] = edge_src: structurally repeat(arange(V),16) -> implicit, unused
  const int*   edge_dst  = (const int*)d_in[2];
  const float* edge_vals = (const float*)d_in[3];
  const float* var_u     = (const float*)d_in[4];
  const float* var_c     = (const float*)d_in[5];
  const float* var_w     = (const float*)d_in[6];
  const float* var_b     = (const float*)d_in[7];
  float* y = (float*)d_out;

  char* ws = (char*)d_ws;
  float*          xu     = (float*)ws;                          // 3,200,000 B
  unsigned short* data_h = (unsigned short*)(ws + 3200000);     // 12,800,000 B
  unsigned short* Bt     = (unsigned short*)(ws + 16000000);    // 65,536 B

  hipLaunchKernelGGL(k0_prep_w, dim3(128), dim3(256), 0, stream, var_w, Bt);
  hipLaunchKernelGGL(k1_prep, dim3((NV + 255) / 256), dim3(256), 0, stream,
                     data, var_u, xu, data_h);
  hipLaunchKernelGGL(k2_main, dim3(NBLOCKS), dim3(256), 0, stream,
                     xu, data_h, edge_dst, edge_vals, Bt, var_c, var_b, y);
}

// Round 5
// 122.433 us; speedup vs baseline: 1.4082x; 1.0468x over previous
//
#include <hip/hip_runtime.h>

typedef _Float16 half2_t __attribute__((ext_vector_type(2)));
typedef _Float16 half8_t __attribute__((ext_vector_type(8)));
typedef __attribute__((ext_vector_type(4))) float f32x4;

#define NV 100000
#define NBLOCKS 6250   // NV / 16 vertices per block-tile

__device__ __forceinline__ unsigned cvt_pk_u(float a, float b) {
  auto h = __builtin_amdgcn_cvt_pkrtz(a, b);   // __fp16 x2
  return __builtin_bit_cast(unsigned, h);
}
__device__ __forceinline__ half2_t u2h(unsigned u) { return __builtin_bit_cast(half2_t, u); }
__device__ __forceinline__ unsigned h2u(half2_t h) { return __builtin_bit_cast(unsigned, h); }
// duplicate fp16 halves: (h0,h0) / (h1,h1)
__device__ __forceinline__ unsigned dup_lo(unsigned q) {
  return __builtin_amdgcn_perm(q, q, 0x01000100u);
}
__device__ __forceinline__ unsigned dup_hi(unsigned q) {
  return __builtin_amdgcn_perm(q, q, 0x03020302u);
}

// K0: Bt[d][k] = fp16(var_w[k*64 + d]);  k = m*64+c, flat var_w is [8][64][64]
__global__ __launch_bounds__(256) void k0_prep_w(const float* __restrict__ var_w,
                                                 unsigned short* __restrict__ Bt) {
  int t = blockIdx.x * 256 + threadIdx.x;
  if (t >= 64 * 512) return;
  int d = t >> 9, k = t & 511;
  _Float16 h = (_Float16)var_w[k * 64 + d];
  Bt[t] = __builtin_bit_cast(unsigned short, h);
}

// K1: x_u[v][8] = data[v] @ var_u ; data_h[v][64] = fp16(data[v])
__global__ __launch_bounds__(256) void k1_prep(const float* __restrict__ data,
                                               const float* __restrict__ var_u,
                                               float* __restrict__ xu,
                                               unsigned short* __restrict__ data_h) {
  __shared__ float u_lds[512];   // var_u [c][w]
  int tid = threadIdx.x;
  u_lds[tid] = var_u[tid];
  u_lds[tid + 256] = var_u[tid + 256];
  __syncthreads();
  int v = blockIdx.x * 256 + tid;
  if (v >= NV) return;
  const float4* dp = (const float4*)(data + v * 64);
  float acc[8];
#pragma unroll
  for (int w = 0; w < 8; ++w) acc[w] = 0.f;
  uint2* ob = (uint2*)(data_h + v * 64);
#pragma unroll
  for (int cc = 0; cc < 16; ++cc) {
    float4 d4 = dp[cc];
    int c0 = cc * 4;
#pragma unroll
    for (int w = 0; w < 8; ++w)
      acc[w] += d4.x * u_lds[(c0 + 0) * 8 + w] + d4.y * u_lds[(c0 + 1) * 8 + w]
              + d4.z * u_lds[(c0 + 2) * 8 + w] + d4.w * u_lds[(c0 + 3) * 8 + w];
    uint2 pk;
    pk.x = cvt_pk_u(d4.x, d4.y);
    pk.y = cvt_pk_u(d4.z, d4.w);
    ob[cc] = pk;
  }
#pragma unroll
  for (int w = 0; w < 8; ++w) xu[v * 8 + w] = acc[w];
}

// K2: one 16-vertex tile per 256-thread block; 4 waves x 4 rows each.
// LDS = 16 KiB/block -> 8 blocks/CU (wave-limit bound, 100% occupancy ceiling).
// Phase B: softmax + fp16 pk_fma aggregation -> LDS agg[16][512] (fp16, swizzled).
// Phase C: 16x64 tile via mfma_f32_16x16x32_f16; wave w owns columns [16w,16w+16).
__global__ __launch_bounds__(256) void k2_main(const float* __restrict__ xu,
    const unsigned short* __restrict__ data_h,
    const int* __restrict__ edge_dst,
    const float* __restrict__ edge_vals,
    const unsigned short* __restrict__ Bt,
    const float* __restrict__ var_c,
    const float* __restrict__ var_b,
    float* __restrict__ y) {
  __shared__ __align__(16) char aggmem[16 * 1024];  // 16 rows x 1024B (512 fp16)
  int tid = threadIdx.x;
  int wave = tid >> 6;
  int l = tid & 63;
  int vbase = blockIdx.x * 16;
  int rbase = wave * 4;
  int m = l & 7;        // weight-matrix index (phase B)
  int jj = l >> 3;      // c-oct index / edge sub-index (phase B)
  int q4 = l >> 4;      // quarter-wave (MFMA k-chunk)
  float cm = var_c[m];

  // ---- software-pipelined phase B: 4 rows per wave ----
  int dstC[2], dstN[2];
  float evC[2], evN[2], xudC[2], xumC, xumN;
#pragma unroll
  for (int p = 0; p < 2; ++p) {
    int e0 = (vbase + rbase + 0) * 16 + jj + 8 * p;
    int e1 = (vbase + rbase + 1) * 16 + jj + 8 * p;
    dstC[p] = edge_dst[e0];  evC[p] = edge_vals[e0];
    dstN[p] = edge_dst[e1];  evN[p] = edge_vals[e1];
  }
  xumC = xu[(vbase + rbase + 0) * 8 + m];
  xumN = xu[(vbase + rbase + 1) * 8 + m];
#pragma unroll
  for (int p = 0; p < 2; ++p) xudC[p] = xu[dstC[p] * 8 + m];

#pragma unroll
  for (int rr = 0; rr < 4; ++rr) {
    int r = rbase + rr;
    // 1. softmax math for vertex r (all inputs resident)
    float q01[2];
#pragma unroll
    for (int p = 0; p < 2; ++p) {
      float ex = __expf(xumC - xudC[p] + cm);
      float s = ex;
      s += __shfl_xor(s, 1);
      s += __shfl_xor(s, 2);
      s += __shfl_xor(s, 4);
      q01[p] = ex * __builtin_amdgcn_rcpf(s) * evC[p];
    }
    unsigned q2u = cvt_pk_u(q01[0], q01[1]);

    // 2. issue future-stage loads (hidden under this vertex's sweep)
    float xudN[2];
    int dstF[2]; float evF[2], xumF;
    if (rr + 1 < 4) {
#pragma unroll
      for (int p = 0; p < 2; ++p) xudN[p] = xu[dstN[p] * 8 + m];
    }
    if (rr + 2 < 4) {
#pragma unroll
      for (int p = 0; p < 2; ++p) {
        int e = (vbase + r + 2) * 16 + jj + 8 * p;
        dstF[p] = edge_dst[e];  evF[p] = edge_vals[e];
      }
      xumF = xu[(vbase + r + 2) * 8 + m];
    }

    // 3. broadcast dst/q, batch-issue all 16 gathers
    int dstj[16];
#pragma unroll
    for (int j = 0; j < 16; ++j) dstj[j] = __shfl(dstC[j >> 3], (j & 7) << 3);
    unsigned qj2[8];
#pragma unroll
    for (int jq = 0; jq < 8; ++jq) qj2[jq] = __shfl((int)q2u, (jq << 3) | m);
    uint4 g[16];
#pragma unroll
    for (int j = 0; j < 16; ++j)
      g[j] = *(const uint4*)(data_h + dstj[j] * 64 + jj * 8);

    // 4. packed-fp16 FMA sweep: edges (jq, jq+8); acc2[w] holds elems (2w,2w+1)
    half2_t acc2[4];
#pragma unroll
    for (int i = 0; i < 4; ++i) acc2[i] = half2_t{(_Float16)0, (_Float16)0};
#pragma unroll
    for (int jq = 0; jq < 8; ++jq) {
      uint4 A = g[jq], B = g[jq + 8];
      half2_t qa = u2h(dup_lo(qj2[jq]));   // (q_jq,   q_jq)
      half2_t qb = u2h(dup_hi(qj2[jq]));   // (q_jq+8, q_jq+8)
      acc2[0] += u2h(A.x) * qa;  acc2[0] += u2h(B.x) * qb;
      acc2[1] += u2h(A.y) * qa;  acc2[1] += u2h(B.y) * qb;
      acc2[2] += u2h(A.z) * qa;  acc2[2] += u2h(B.z) * qb;
      acc2[3] += u2h(A.w) * qa;  acc2[3] += u2h(B.w) * qb;
    }

    // 5. store agg row r: element k = m*64 + jj*8 + i (byte 2k), XOR-swizzled
    uint4 pk;
    pk.x = h2u(acc2[0]);
    pk.y = h2u(acc2[1]);
    pk.z = h2u(acc2[2]);
    pk.w = h2u(acc2[3]);
    int bir = m * 128 + jj * 16;
    int bo = bir ^ ((bir >> 3) & 0x70) ^ ((r & 7) << 4);
    *(uint4*)(aggmem + r * 1024 + bo) = pk;

    // 6. rotate pipeline stages
#pragma unroll
    for (int p = 0; p < 2; ++p) {
      dstC[p] = dstN[p]; evC[p] = evN[p]; xudC[p] = xudN[p];
      dstN[p] = dstF[p]; evN[p] = evF[p];
    }
    xumC = xumN; xumN = xumF;
  }

  __syncthreads();   // all 16 rows complete (4 waves)

  // ---- phase C: 16x64 tile; wave w owns columns [16w, 16w+16) ----
  f32x4 C = {0.f, 0.f, 0.f, 0.f};
  int row = l & 15;
#pragma unroll
  for (int ks = 0; ks < 16; ++ks) {
    int bir = ks * 64 + q4 * 16;
    int bo = bir ^ ((bir >> 3) & 0x70) ^ ((row & 7) << 4);
    half8_t afrag = *(const half8_t*)(aggmem + row * 1024 + bo);  // A[row][ks*32+q4*8..+8]
    int col = row + wave * 16;
    half8_t bfrag = *(const half8_t*)(Bt + (col * 512 + ks * 32 + q4 * 8));
    C = __builtin_amdgcn_mfma_f32_16x16x32_f16(afrag, bfrag, C, 0, 0, 0);
  }
  int col = row + wave * 16;
  float bias = var_b[col];
#pragma unroll
  for (int i = 0; i < 4; ++i) {
    y[(vbase + q4 * 4 + i) * 64 + col] = C[i] + bias;  // C/D: col=l&15, row=q4*4+i
  }
}

extern "C" void kernel_launch(void* const* d_in, const int* in_sizes, int n_in,
                              void* d_out, int out_size, void* d_ws, size_t ws_size,
                              hipStream_t stream) {
  const float* data      = (const float*)d_in[0];
  // d_in[1] = edge_src: structurally repeat(arange(V),16) -> implicit, unused
  const int*   edge_dst  = (const int*)d_in[2];
  const float* edge_vals = (const float*)d_in[3];
  const float* var_u     = (const float*)d_in[4];
  const float* var_c     = (const float*)d_in[5];
  const float* var_w     = (const float*)d_in[6];
  const float* var_b     = (const float*)d_in[7];
  float* y = (float*)d_out;

  char* ws = (char*)d_ws;
  float*          xu     = (float*)ws;                          // 3,200,000 B
  unsigned short* data_h = (unsigned short*)(ws + 3200000);     // 12,800,000 B
  unsigned short* Bt     = (unsigned short*)(ws + 16000000);    // 65,536 B

  hipLaunchKernelGGL(k0_prep_w, dim3(128), dim3(256), 0, stream, var_w, Bt);
  hipLaunchKernelGGL(k1_prep, dim3((NV + 255) / 256), dim3(256), 0, stream,
                     data, var_u, xu, data_h);
  hipLaunchKernelGGL(k2_main, dim3(NBLOCKS), dim3(256), 0, stream,
                     xu, data_h, edge_dst, edge_vals, Bt, var_c, var_b, y);
}

// Round 6
// 105.119 us; speedup vs baseline: 1.6402x; 1.1647x over previous
//
#include <hip/hip_runtime.h>

typedef _Float16 half2_t __attribute__((ext_vector_type(2)));
typedef _Float16 half8_t __attribute__((ext_vector_type(8)));
typedef __attribute__((ext_vector_type(4))) float f32x4;

#define NV 100000
#define NBLOCKS 6250   // NV / 16 vertices per block-tile

__device__ __forceinline__ unsigned cvt_pk_u(float a, float b) {
  auto h = __builtin_amdgcn_cvt_pkrtz(a, b);   // __fp16 x2
  return __builtin_bit_cast(unsigned, h);
}
__device__ __forceinline__ half2_t u2h(unsigned u) { return __builtin_bit_cast(half2_t, u); }
__device__ __forceinline__ unsigned h2u(half2_t h) { return __builtin_bit_cast(unsigned, h); }
// duplicate fp16 halves: (h0,h0) / (h1,h1)
__device__ __forceinline__ unsigned dup_lo(unsigned q) {
  return __builtin_amdgcn_perm(q, q, 0x01000100u);
}
__device__ __forceinline__ unsigned dup_hi(unsigned q) {
  return __builtin_amdgcn_perm(q, q, 0x03020302u);
}
// async global->LDS, 16B per lane; dest = lds base + lane*16 (HW rule)
__device__ __forceinline__ void load16_to_lds(const void* g, void* s) {
  __builtin_amdgcn_global_load_lds(
      (const __attribute__((address_space(1))) unsigned int*)g,
      (__attribute__((address_space(3))) unsigned int*)s, 16, 0, 0);
}

// K0: Bt[d][k] = fp16(var_w[k*64 + d]);  k = m*64+c, flat var_w is [8][64][64]
__global__ __launch_bounds__(256) void k0_prep_w(const float* __restrict__ var_w,
                                                 unsigned short* __restrict__ Bt) {
  int t = blockIdx.x * 256 + threadIdx.x;
  if (t >= 64 * 512) return;
  int d = t >> 9, k = t & 511;
  _Float16 h = (_Float16)var_w[k * 64 + d];
  Bt[t] = __builtin_bit_cast(unsigned short, h);
}

// K1: x_u[v][8] = data[v] @ var_u ; data_h[v][64] = fp16(data[v])
__global__ __launch_bounds__(256) void k1_prep(const float* __restrict__ data,
                                               const float* __restrict__ var_u,
                                               float* __restrict__ xu,
                                               unsigned short* __restrict__ data_h) {
  __shared__ float u_lds[512];   // var_u [c][w]
  int tid = threadIdx.x;
  u_lds[tid] = var_u[tid];
  u_lds[tid + 256] = var_u[tid + 256];
  __syncthreads();
  int v = blockIdx.x * 256 + tid;
  if (v >= NV) return;
  const float4* dp = (const float4*)(data + v * 64);
  float acc[8];
#pragma unroll
  for (int w = 0; w < 8; ++w) acc[w] = 0.f;
  uint2* ob = (uint2*)(data_h + v * 64);
#pragma unroll
  for (int cc = 0; cc < 16; ++cc) {
    float4 d4 = dp[cc];
    int c0 = cc * 4;
#pragma unroll
    for (int w = 0; w < 8; ++w)
      acc[w] += d4.x * u_lds[(c0 + 0) * 8 + w] + d4.y * u_lds[(c0 + 1) * 8 + w]
              + d4.z * u_lds[(c0 + 2) * 8 + w] + d4.w * u_lds[(c0 + 3) * 8 + w];
    uint2 pk;
    pk.x = cvt_pk_u(d4.x, d4.y);
    pk.y = cvt_pk_u(d4.z, d4.w);
    ob[cc] = pk;
  }
#pragma unroll
  for (int w = 0; w < 8; ++w) xu[v * 8 + w] = acc[w];
}

// K2: one 16-vertex tile per 256-thread block; 4 waves x 4 rows each.
// Phase B: neighbor rows staged to LDS via 2x global_load_lds per vertex
// (64 distinct lane-addresses each — no 8x broadcast addressing), double-
// buffered with counted vmcnt. Sweep feeds from LDS (immediate offsets).
// Phase C: 16x64 tile via mfma_f32_16x16x32_f16; wave w owns cols [16w,16w+16).
__global__ __launch_bounds__(256, 5) void k2_main(const float* __restrict__ xu,
    const unsigned short* __restrict__ data_h,
    const int* __restrict__ edge_dst,
    const float* __restrict__ edge_vals,
    const unsigned short* __restrict__ Bt,
    const float* __restrict__ var_c,
    const float* __restrict__ var_b,
    float* __restrict__ y) {
  __shared__ __align__(16) char aggmem[16 * 1024];        // agg[16 rows][1024B]
  __shared__ __align__(16) char xstage[4][2][2048];       // per-wave double buffer
  int tid = threadIdx.x;
  int wave = tid >> 6;
  int l = tid & 63;
  int vbase = blockIdx.x * 16;
  int rbase = wave * 4;
  int m = l & 7;        // weight-matrix index (phase B)
  int jj = l >> 3;      // c-oct index (phase B)
  int q4 = l >> 4;      // quarter-wave (MFMA k-chunk)
  float cm = var_c[m];
  char* xs = &xstage[wave][0][0];

  // ---- prologue: ALL softmax-input loads for this wave's 4 rows ----
  // (keeps the main loop free of compiler-scheduled VMEM so vmcnt counts hold)
  int dstS[4], dstP[4][2];
  float evP[4][2], xum[4], xud[4][2];
#pragma unroll
  for (int i = 0; i < 4; ++i) {
    int v = vbase + rbase + i;
    dstS[i] = edge_dst[v * 16 + (l >> 2)];     // staging layout: lane l -> row l>>2
#pragma unroll
    for (int p = 0; p < 2; ++p) {
      int e = v * 16 + jj + 8 * p;
      dstP[i][p] = edge_dst[e];
      evP[i][p] = edge_vals[e];
    }
    xum[i] = xu[v * 8 + m];
  }
  // stage row 0 into buf 0 (pinned window: nothing may slip between stages & fence)
  asm volatile("" ::: "memory");
  {
    const char* s0 = (const char*)data_h + (size_t)dstS[0] * 128 + (l & 3) * 16;
    load16_to_lds(s0, xs);
    load16_to_lds(s0 + 64, xs + 1024);
  }
  asm volatile("" ::: "memory");
#pragma unroll
  for (int i = 0; i < 4; ++i)
#pragma unroll
    for (int p = 0; p < 2; ++p) xud[i][p] = xu[dstP[i][p] * 8 + m];

  // lane-constant LDS read base: chunk jj lives at (jj>>2)*1024 + (jj&3)*16 (+row*64)
  const uint4* xb = (const uint4*)(xs + (jj >> 2) * 1024 + (jj & 3) * 16);

#pragma unroll
  for (int r = 0; r < 4; ++r) {
    // 1. stage vertex r+1 into the other buffer (async, stays in flight)
    if (r < 3) {
      const char* s = (const char*)data_h + (size_t)dstS[r + 1] * 128 + (l & 3) * 16;
      char* d = xs + ((r + 1) & 1) * 2048;
      asm volatile("" ::: "memory");
      load16_to_lds(s, d);
      load16_to_lds(s + 64, d + 1024);
      asm volatile("" ::: "memory");
    }

    // 2. softmax for vertex r (register-only; no VMEM here)
    float q01[2];
#pragma unroll
    for (int p = 0; p < 2; ++p) {
      float ex = __expf(xum[r] - xud[r][p] + cm);
      float ssum = ex;
      ssum += __shfl_xor(ssum, 1);
      ssum += __shfl_xor(ssum, 2);
      ssum += __shfl_xor(ssum, 4);
      q01[p] = ex * __builtin_amdgcn_rcpf(ssum) * evP[r][p];
    }
    unsigned q2u = cvt_pk_u(q01[0], q01[1]);
    unsigned qj2[8];
#pragma unroll
    for (int jq = 0; jq < 8; ++jq) qj2[jq] = __shfl((int)q2u, (jq << 3) | m);

    // 3. wait for THIS row's staged data (keep next row's 2 loads in flight)
    if (r < 3) asm volatile("s_waitcnt vmcnt(2)" ::: "memory");
    else       asm volatile("s_waitcnt vmcnt(0)" ::: "memory");

    // 4. packed-fp16 FMA sweep from LDS: rows jq & jq+8, chunk jj
    int bsel = (r & 1) * 128;   // uint4 index: buffer select (+2048B)
    half2_t acc2[4];
#pragma unroll
    for (int i = 0; i < 4; ++i) acc2[i] = half2_t{(_Float16)0, (_Float16)0};
#pragma unroll
    for (int jq = 0; jq < 8; ++jq) {
      uint4 A = xb[bsel + jq * 4];
      uint4 B = xb[bsel + (jq + 8) * 4];
      half2_t qa = u2h(dup_lo(qj2[jq]));   // (q_jq,   q_jq)
      half2_t qb = u2h(dup_hi(qj2[jq]));   // (q_jq+8, q_jq+8)
      acc2[0] += u2h(A.x) * qa;  acc2[0] += u2h(B.x) * qb;
      acc2[1] += u2h(A.y) * qa;  acc2[1] += u2h(B.y) * qb;
      acc2[2] += u2h(A.z) * qa;  acc2[2] += u2h(B.z) * qb;
      acc2[3] += u2h(A.w) * qa;  acc2[3] += u2h(B.w) * qb;
    }

    // 5. store agg row: element k = m*64 + jj*8 + i (byte 2k), XOR-swizzled
    int rrow = rbase + r;
    uint4 pk;
    pk.x = h2u(acc2[0]);
    pk.y = h2u(acc2[1]);
    pk.z = h2u(acc2[2]);
    pk.w = h2u(acc2[3]);
    int bir = m * 128 + jj * 16;
    int bo = bir ^ ((bir >> 3) & 0x70) ^ ((rrow & 7) << 4);
    *(uint4*)(aggmem + rrow * 1024 + bo) = pk;
  }

  __syncthreads();   // all 16 rows complete (4 waves)

  // ---- phase C: 16x64 tile; wave w owns columns [16w, 16w+16) ----
  f32x4 C = {0.f, 0.f, 0.f, 0.f};
  int row = l & 15;
#pragma unroll
  for (int ks = 0; ks < 16; ++ks) {
    int bir = ks * 64 + q4 * 16;
    int bo = bir ^ ((bir >> 3) & 0x70) ^ ((row & 7) << 4);
    half8_t afrag = *(const half8_t*)(aggmem + row * 1024 + bo);  // A[row][ks*32+q4*8..+8]
    int col = row + wave * 16;
    half8_t bfrag = *(const half8_t*)(Bt + (col * 512 + ks * 32 + q4 * 8));
    C = __builtin_amdgcn_mfma_f32_16x16x32_f16(afrag, bfrag, C, 0, 0, 0);
  }
  int col = row + wave * 16;
  float bias = var_b[col];
#pragma unroll
  for (int i = 0; i < 4; ++i) {
    y[(vbase + q4 * 4 + i) * 64 + col] = C[i] + bias;  // C/D: col=l&15, row=q4*4+i
  }
}

extern "C" void kernel_launch(void* const* d_in, const int* in_sizes, int n_in,
                              void* d_out, int out_size, void* d_ws, size_t ws_size,
                              hipStream_t stream) {
  const float* data      = (const float*)d_in[0];
  // d_in[1] = edge_src: structurally repeat(arange(V),16) -> implicit, unused
  const int*   edge_dst  = (const int*)d_in[2];
  const float* edge_vals = (const float*)d_in[3];
  const float* var_u     = (const float*)d_in[4];
  const float* var_c     = (const float*)d_in[5];
  const float* var_w     = (const float*)d_in[6];
  const float* var_b     = (const float*)d_in[7];
  float* y = (float*)d_out;

  char* ws = (char*)d_ws;
  float*          xu     = (float*)ws;                          // 3,200,000 B
  unsigned short* data_h = (unsigned short*)(ws + 3200000);     // 12,800,000 B
  unsigned short* Bt     = (unsigned short*)(ws + 16000000);    // 65,536 B

  hipLaunchKernelGGL(k0_prep_w, dim3(128), dim3(256), 0, stream, var_w, Bt);
  hipLaunchKernelGGL(k1_prep, dim3((NV + 255) / 256), dim3(256), 0, stream,
                     data, var_u, xu, data_h);
  hipLaunchKernelGGL(k2_main, dim3(NBLOCKS), dim3(256), 0, stream,
                     xu, data_h, edge_dst, edge_vals, Bt, var_c, var_b, y);
}

// Round 7
// 101.503 us; speedup vs baseline: 1.6986x; 1.0356x over previous
//
#include <hip/hip_runtime.h>

typedef _Float16 half2_t __attribute__((ext_vector_type(2)));
typedef _Float16 half8_t __attribute__((ext_vector_type(8)));
typedef __attribute__((ext_vector_type(4))) float f32x4;

#define NV 100000
#define NBLOCKS 6250   // NV / 16 vertices per block-tile

__device__ __forceinline__ unsigned cvt_pk_u(float a, float b) {
  auto h = __builtin_amdgcn_cvt_pkrtz(a, b);   // __fp16 x2
  return __builtin_bit_cast(unsigned, h);
}
__device__ __forceinline__ half2_t u2h(unsigned u) { return __builtin_bit_cast(half2_t, u); }
__device__ __forceinline__ unsigned h2u(half2_t h) { return __builtin_bit_cast(unsigned, h); }
// duplicate fp16 halves: (h0,h0) / (h1,h1)
__device__ __forceinline__ unsigned dup_lo(unsigned q) {
  return __builtin_amdgcn_perm(q, q, 0x01000100u);
}
__device__ __forceinline__ unsigned dup_hi(unsigned q) {
  return __builtin_amdgcn_perm(q, q, 0x03020302u);
}
// async global->LDS, 16B per lane; dest = lds base + lane*16 (HW rule)
__device__ __forceinline__ void load16_to_lds(const void* g, void* s) {
  __builtin_amdgcn_global_load_lds(
      (const __attribute__((address_space(1))) unsigned int*)g,
      (__attribute__((address_space(3))) unsigned int*)s, 16, 0, 0);
}

// K0: Bt[d][k] = fp16(var_w[k*64 + d]);  k = m*64+c, flat var_w is [8][64][64]
__global__ __launch_bounds__(256) void k0_prep_w(const float* __restrict__ var_w,
                                                 unsigned short* __restrict__ Bt) {
  int t = blockIdx.x * 256 + threadIdx.x;
  if (t >= 64 * 512) return;
  int d = t >> 9, k = t & 511;
  _Float16 h = (_Float16)var_w[k * 64 + d];
  Bt[t] = __builtin_bit_cast(unsigned short, h);
}

// K1: x_u[v][8] = data[v] @ var_u ; data_h[v][64] = fp16(data[v])
__global__ __launch_bounds__(256) void k1_prep(const float* __restrict__ data,
                                               const float* __restrict__ var_u,
                                               float* __restrict__ xu,
                                               unsigned short* __restrict__ data_h) {
  __shared__ float u_lds[512];   // var_u [c][w]
  int tid = threadIdx.x;
  u_lds[tid] = var_u[tid];
  u_lds[tid + 256] = var_u[tid + 256];
  __syncthreads();
  int v = blockIdx.x * 256 + tid;
  if (v >= NV) return;
  const float4* dp = (const float4*)(data + v * 64);
  float acc[8];
#pragma unroll
  for (int w = 0; w < 8; ++w) acc[w] = 0.f;
  uint2* ob = (uint2*)(data_h + v * 64);
#pragma unroll
  for (int cc = 0; cc < 16; ++cc) {
    float4 d4 = dp[cc];
    int c0 = cc * 4;
#pragma unroll
    for (int w = 0; w < 8; ++w)
      acc[w] += d4.x * u_lds[(c0 + 0) * 8 + w] + d4.y * u_lds[(c0 + 1) * 8 + w]
              + d4.z * u_lds[(c0 + 2) * 8 + w] + d4.w * u_lds[(c0 + 3) * 8 + w];
    uint2 pk;
    pk.x = cvt_pk_u(d4.x, d4.y);
    pk.y = cvt_pk_u(d4.z, d4.w);
    ob[cc] = pk;
  }
#pragma unroll
  for (int w = 0; w < 8; ++w) xu[v * 8 + w] = acc[w];
}

// K2: one 16-vertex tile per 256-thread block; 4 waves x 4 rows each.
// Phase B: ALL 4 rows' neighbor data staged to LDS upfront (8x global_load_lds
// in flight per wave = 4-deep pipeline), per-row counted vmcnt(6/4/2/0).
// Sweep feeds from LDS (immediate offsets). Bt pre-loaded to registers.
// Phase C: 16x64 tile via mfma_f32_16x16x32_f16; wave w owns cols [16w,16w+16).
__global__ __launch_bounds__(256, 3) void k2_main(const float* __restrict__ xu,
    const unsigned short* __restrict__ data_h,
    const int* __restrict__ edge_dst,
    const float* __restrict__ edge_vals,
    const unsigned short* __restrict__ Bt,
    const float* __restrict__ var_c,
    const float* __restrict__ var_b,
    float* __restrict__ y) {
  __shared__ __align__(16) char aggmem[16 * 1024];        // agg[16 rows][1024B]
  __shared__ __align__(16) char xstage[4][4][2048];       // per-wave 4-row buffers
  int tid = threadIdx.x;
  int wave = tid >> 6;
  int l = tid & 63;
  int vbase = blockIdx.x * 16;
  int rbase = wave * 4;
  int m = l & 7;        // weight-matrix index (phase B)
  int jj = l >> 3;      // c-oct index (phase B)
  int q4 = l >> 4;      // quarter-wave (MFMA k-chunk)
  float cm = var_c[m];
  char* xs = &xstage[wave][0][0];
  int row = l & 15;
  int col = row + wave * 16;

  // ---- segment 1: all compiler-scheduled global loads ----
  int dstS[4], dstP[4][2];
  float evP[4][2], xum[4], xud[4][2];
#pragma unroll
  for (int i = 0; i < 4; ++i) {
    int v = vbase + rbase + i;
    dstS[i] = edge_dst[v * 16 + (l >> 2)];     // staging layout: lane l -> row l>>2
#pragma unroll
    for (int p = 0; p < 2; ++p) {
      int e = v * 16 + jj + 8 * p;
      dstP[i][p] = edge_dst[e];
      evP[i][p] = edge_vals[e];
    }
    xum[i] = xu[v * 8 + m];
  }
  // Bt fragments for phase C -> registers (issued before xud; both before stages)
  uint4 btf[16];
#pragma unroll
  for (int ks = 0; ks < 16; ++ks)
    btf[ks] = *(const uint4*)(Bt + (col * 512 + ks * 32 + q4 * 8));
#pragma unroll
  for (int i = 0; i < 4; ++i)
#pragma unroll
    for (int p = 0; p < 2; ++p) xud[i][p] = xu[dstP[i][p] * 8 + m];

  // ---- segment 2: issue ALL 8 staging loads (4 rows x 2), pinned window ----
  asm volatile("" ::: "memory");
#pragma unroll
  for (int i = 0; i < 4; ++i) {
    const char* s = (const char*)data_h + (size_t)dstS[i] * 128 + (l & 3) * 16;
    char* d = xs + i * 2048;
    load16_to_lds(s, d);
    load16_to_lds(s + 64, d + 1024);
  }
  asm volatile("" ::: "memory");

  // lane-constant LDS read base: chunk jj lives at (jj>>2)*1024 + (jj&3)*16 (+row*64)
  const uint4* xb = (const uint4*)(xs + (jj >> 2) * 1024 + (jj & 3) * 16);

#pragma unroll
  for (int r = 0; r < 4; ++r) {
    // 1. softmax for vertex r (register-only; compiler waits only for xud here)
    float q01[2];
#pragma unroll
    for (int p = 0; p < 2; ++p) {
      float ex = __expf(xum[r] - xud[r][p] + cm);
      float ssum = ex;
      ssum += __shfl_xor(ssum, 1);
      ssum += __shfl_xor(ssum, 2);
      ssum += __shfl_xor(ssum, 4);
      q01[p] = ex * __builtin_amdgcn_rcpf(ssum) * evP[r][p];
    }
    unsigned q2u = cvt_pk_u(q01[0], q01[1]);
    unsigned qj2[8];
#pragma unroll
    for (int jq = 0; jq < 8; ++jq) qj2[jq] = __shfl((int)q2u, (jq << 3) | m);

    // 2. wait for THIS row's staged data; rows r+1..3 stay in flight
    if (r == 0)      asm volatile("s_waitcnt vmcnt(6)" ::: "memory");
    else if (r == 1) asm volatile("s_waitcnt vmcnt(4)" ::: "memory");
    else if (r == 2) asm volatile("s_waitcnt vmcnt(2)" ::: "memory");
    else             asm volatile("s_waitcnt vmcnt(0)" ::: "memory");

    // 3. packed-fp16 FMA sweep from LDS: rows jq & jq+8, chunk jj
    int bsel = r * 128;   // uint4 index: buffer r (+2048B each)
    half2_t acc2[4];
#pragma unroll
    for (int i = 0; i < 4; ++i) acc2[i] = half2_t{(_Float16)0, (_Float16)0};
#pragma unroll
    for (int jq = 0; jq < 8; ++jq) {
      uint4 A = xb[bsel + jq * 4];
      uint4 B = xb[bsel + (jq + 8) * 4];
      half2_t qa = u2h(dup_lo(qj2[jq]));   // (q_jq,   q_jq)
      half2_t qb = u2h(dup_hi(qj2[jq]));   // (q_jq+8, q_jq+8)
      acc2[0] += u2h(A.x) * qa;  acc2[0] += u2h(B.x) * qb;
      acc2[1] += u2h(A.y) * qa;  acc2[1] += u2h(B.y) * qb;
      acc2[2] += u2h(A.z) * qa;  acc2[2] += u2h(B.z) * qb;
      acc2[3] += u2h(A.w) * qa;  acc2[3] += u2h(B.w) * qb;
    }

    // 4. store agg row: element k = m*64 + jj*8 + i (byte 2k), XOR-swizzled
    int rrow = rbase + r;
    uint4 pk;
    pk.x = h2u(acc2[0]);
    pk.y = h2u(acc2[1]);
    pk.z = h2u(acc2[2]);
    pk.w = h2u(acc2[3]);
    int bir = m * 128 + jj * 16;
    int bo = bir ^ ((bir >> 3) & 0x70) ^ ((rrow & 7) << 4);
    *(uint4*)(aggmem + rrow * 1024 + bo) = pk;
  }

  __syncthreads();   // all 16 rows complete (4 waves)

  // ---- phase C: 16x64 tile; wave w owns columns [16w, 16w+16) ----
  f32x4 C = {0.f, 0.f, 0.f, 0.f};
#pragma unroll
  for (int ks = 0; ks < 16; ++ks) {
    int bir = ks * 64 + q4 * 16;
    int bo = bir ^ ((bir >> 3) & 0x70) ^ ((row & 7) << 4);
    half8_t afrag = *(const half8_t*)(aggmem + row * 1024 + bo);  // A[row][ks*32+q4*8..+8]
    half8_t bfrag = __builtin_bit_cast(half8_t, btf[ks]);
    C = __builtin_amdgcn_mfma_f32_16x16x32_f16(afrag, bfrag, C, 0, 0, 0);
  }
  float bias = var_b[col];
#pragma unroll
  for (int i = 0; i < 4; ++i) {
    y[(vbase + q4 * 4 + i) * 64 + col] = C[i] + bias;  // C/D: col=l&15, row=q4*4+i
  }
}

extern "C" void kernel_launch(void* const* d_in, const int* in_sizes, int n_in,
                              void* d_out, int out_size, void* d_ws, size_t ws_size,
                              hipStream_t stream) {
  const float* data      = (const float*)d_in[0];
  // d_in[1] = edge_src: structurally repeat(arange(V),16) -> implicit, unused
  const int*   edge_dst  = (const int*)d_in[2];
  const float* edge_vals = (const float*)d_in[3];
  const float* var_u     = (const float*)d_in[4];
  const float* var_c     = (const float*)d_in[5];
  const float* var_w     = (const float*)d_in[6];
  const float* var_b     = (const float*)d_in[7];
  float* y = (float*)d_out;

  char* ws = (char*)d_ws;
  float*          xu     = (float*)ws;                          // 3,200,000 B
  unsigned short* data_h = (unsigned short*)(ws + 3200000);     // 12,800,000 B
  unsigned short* Bt     = (unsigned short*)(ws + 16000000);    // 65,536 B

  hipLaunchKernelGGL(k0_prep_w, dim3(128), dim3(256), 0, stream, var_w, Bt);
  hipLaunchKernelGGL(k1_prep, dim3((NV + 255) / 256), dim3(256), 0, stream,
                     data, var_u, xu, data_h);
  hipLaunchKernelGGL(k2_main, dim3(NBLOCKS), dim3(256), 0, stream,
                     xu, data_h, edge_dst, edge_vals, Bt, var_c, var_b, y);
}

// Round 8
// 93.304 us; speedup vs baseline: 1.8479x; 1.0879x over previous
//
#include <hip/hip_runtime.h>

typedef _Float16 half2_t __attribute__((ext_vector_type(2)));
typedef _Float16 half8_t __attribute__((ext_vector_type(8)));
typedef __attribute__((ext_vector_type(4))) float f32x4;

#define NV 100000
#define NT 12500        // tiles of 8 vertices
#define GRID 768        // 3 blocks/CU * 256 CUs, grid-stride over tiles
#define ROWB 160        // rowbuf record: 128B fp16 feats + 32B fp32 xu

__device__ __forceinline__ unsigned cvt_pk_u(float a, float b) {
  auto h = __builtin_amdgcn_cvt_pkrtz(a, b);
  return __builtin_bit_cast(unsigned, h);
}
__device__ __forceinline__ half2_t u2h(unsigned u) { return __builtin_bit_cast(half2_t, u); }
__device__ __forceinline__ unsigned h2u(half2_t h) { return __builtin_bit_cast(unsigned, h); }
__device__ __forceinline__ unsigned dup_lo(unsigned q) {
  return __builtin_amdgcn_perm(q, q, 0x01000100u);
}
__device__ __forceinline__ unsigned dup_hi(unsigned q) {
  return __builtin_amdgcn_perm(q, q, 0x03020302u);
}
__device__ __forceinline__ void load16_to_lds(const void* g, void* s) {
  __builtin_amdgcn_global_load_lds(
      (const __attribute__((address_space(1))) unsigned int*)g,
      (__attribute__((address_space(3))) unsigned int*)s, 16, 0, 0);
}

// K0: Bt[d][k] = fp16(var_w[k*64 + d]);  k = m*64+c
__global__ __launch_bounds__(256) void k0_prep_w(const float* __restrict__ var_w,
                                                 unsigned short* __restrict__ Bt) {
  int t = blockIdx.x * 256 + threadIdx.x;
  if (t >= 64 * 512) return;
  int d = t >> 9, k = t & 511;
  _Float16 h = (_Float16)var_w[k * 64 + d];
  Bt[t] = __builtin_bit_cast(unsigned short, h);
}

// K1: rowbuf[v] = {fp16 data[v][0..64), fp32 xu[v][0..8)}  (160 B record)
__global__ __launch_bounds__(256) void k1_prep(const float* __restrict__ data,
                                               const float* __restrict__ var_u,
                                               char* __restrict__ rowbuf) {
  __shared__ float u_lds[512];
  int tid = threadIdx.x;
  u_lds[tid] = var_u[tid];
  u_lds[tid + 256] = var_u[tid + 256];
  __syncthreads();
  int v = blockIdx.x * 256 + tid;
  if (v >= NV) return;
  const float4* dp = (const float4*)(data + v * 64);
  char* out = rowbuf + (size_t)v * ROWB;
  float acc[8];
#pragma unroll
  for (int w = 0; w < 8; ++w) acc[w] = 0.f;
  unsigned rp[32];
#pragma unroll
  for (int cc = 0; cc < 16; ++cc) {
    float4 d4 = dp[cc];
    int c0 = cc * 4;
#pragma unroll
    for (int w = 0; w < 8; ++w)
      acc[w] += d4.x * u_lds[(c0 + 0) * 8 + w] + d4.y * u_lds[(c0 + 1) * 8 + w]
              + d4.z * u_lds[(c0 + 2) * 8 + w] + d4.w * u_lds[(c0 + 3) * 8 + w];
    rp[cc * 2]     = cvt_pk_u(d4.x, d4.y);
    rp[cc * 2 + 1] = cvt_pk_u(d4.z, d4.w);
  }
#pragma unroll
  for (int q = 0; q < 8; ++q) {
    uint4 pk = {rp[q * 4], rp[q * 4 + 1], rp[q * 4 + 2], rp[q * 4 + 3]};
    ((uint4*)out)[q] = pk;
  }
  float4 xa = {acc[0], acc[1], acc[2], acc[3]};
  float4 xb = {acc[4], acc[5], acc[6], acc[7]};
  ((float4*)(out + 128))[0] = xa;
  ((float4*)(out + 128))[1] = xb;
}

// K2: persistent grid-stride over 8-vertex tiles; 4 waves x 2 vertices.
// Pipeline: lin loads 2 tiles ahead, LDS stages (global_load_lds, 5/wave,
// fused feats+xu rows) 1 tile ahead (double buffer), counted vmcnt(8) waits,
// raw barriers (no vmcnt drain). Phase C: 16x64 via mfma_f32_16x16x32_f16.
__global__ __launch_bounds__(256, 3) void k2_main(
    const char* __restrict__ rowbuf,
    const int* __restrict__ edge_dst,
    const float* __restrict__ edge_vals,
    const unsigned short* __restrict__ Bt,
    const float* __restrict__ var_c,
    const float* __restrict__ var_b,
    float* __restrict__ y) {
  __shared__ __align__(16) char aggmem[8 * 1024];       // agg[8 rows][1024B]
  __shared__ __align__(16) char xstage[2][4][5120];     // dbuf x wave x (2v*16rows*160B)
  int tid = threadIdx.x;
  int wave = tid >> 6;
  int l = tid & 63;
  int m = l & 7;
  int jj = l >> 3;
  int q4 = l >> 4;
  int col = (l & 15) + wave * 16;

  // ---- one-time prologue loads ----
  uint4 btf[16];
#pragma unroll
  for (int ks = 0; ks < 16; ++ks)
    btf[ks] = *(const uint4*)(Bt + (col * 512 + ks * 32 + q4 * 8));
  float cm = var_c[m];
  float bias = var_b[col];

  // rotating lin sets: A=cur(t), B=next(t+G), F=future(t+2G)
  int dstA, dstB, dstF;
  float evA, evB, evF, xmA, xmB, xmF;
  int lsel = l & 31;
  int xp = (l >> 3) & 1, xm_ = l & 7;

  int t0 = blockIdx.x;
  {
    int vt = t0 * 8 + wave * 2;
    dstA = edge_dst[vt * 16 + lsel];
    evA  = edge_vals[vt * 16 + lsel];
    xmA  = *(const float*)(rowbuf + (size_t)(vt + xp) * ROWB + 128 + xm_ * 4);
  }
  {
    int t1 = (t0 + GRID < NT) ? t0 + GRID : t0;
    int vt = t1 * 8 + wave * 2;
    dstB = edge_dst[vt * 16 + lsel];
    evB  = edge_vals[vt * 16 + lsel];
    xmB  = *(const float*)(rowbuf + (size_t)(vt + xp) * ROWB + 128 + xm_ * 4);
  }
  asm volatile("s_waitcnt vmcnt(3)" ::: "memory");   // all but lin(t+G) done

  // stage tile t0 into buf 0 (5 x global_load_lds: 320 slots of 16B)
  {
    char* sb = &xstage[0][wave][0];
    asm volatile("" ::: "memory");
#pragma unroll
    for (int i = 0; i < 5; ++i) {
      int s = i * 64 + l;
      int p = (s * 410) >> 16;          // s/160
      int rem = s - p * 160;
      int j = (rem * 6554) >> 16;       // rem/10
      int ch = rem - j * 10;
      int dst = __builtin_amdgcn_ds_bpermute((p * 16 + j) << 2, dstA);
      load16_to_lds(rowbuf + (size_t)dst * ROWB + ch * 16, sb + i * 1024);
    }
    asm volatile("" ::: "memory");
  }
  // invariant entering loop: outstanding = lin(t+G) 3 + stages(t) 5 = 8

  int k = 0;
  for (int t = t0; t < NT; t += GRID, ++k) {
    // alpha: lin loads for t+2G (clamped)
    {
      int tf = (t + 2 * GRID < NT) ? t + 2 * GRID : t;
      int vt = tf * 8 + wave * 2;
      dstF = edge_dst[vt * 16 + lsel];
      evF  = edge_vals[vt * 16 + lsel];
      xmF  = *(const float*)(rowbuf + (size_t)(vt + xp) * ROWB + 128 + xm_ * 4);
    }
    asm volatile("" ::: "memory");
    // beta: wait lin(t+G) ready, issue stages(t+G) into other buffer
    asm volatile("s_waitcnt vmcnt(8)" ::: "memory");
    {
      char* sb = &xstage[(k + 1) & 1][wave][0];
      asm volatile("" ::: "memory");
#pragma unroll
      for (int i = 0; i < 5; ++i) {
        int s = i * 64 + l;
        int p = (s * 410) >> 16;
        int rem = s - p * 160;
        int j = (rem * 6554) >> 16;
        int ch = rem - j * 10;
        int dst = __builtin_amdgcn_ds_bpermute((p * 16 + j) << 2, dstB);
        load16_to_lds(rowbuf + (size_t)dst * ROWB + ch * 16, sb + i * 1024);
      }
      asm volatile("" ::: "memory");
    }
    // gamma: wait stages(t) complete (>=9th-oldest => retired at vmcnt(8))
    asm volatile("s_waitcnt vmcnt(8)" ::: "memory");

    const char* xs = &xstage[k & 1][wave][0];
#pragma unroll
    for (int p = 0; p < 2; ++p) {
      const char* xsp = xs + p * 2560;
      // softmax inputs: xud from staged record, ev/xum from lin regs
      float xud0 = *(const float*)(xsp + jj * 160 + 128 + m * 4);
      float xud1 = *(const float*)(xsp + (jj + 8) * 160 + 128 + m * 4);
      float evs0 = __shfl(evA, p * 16 + jj);
      float evs1 = __shfl(evA, p * 16 + jj + 8);
      float xmv  = __shfl(xmA, (p << 3) | m);
      float ex0 = __expf(xmv - xud0 + cm);
      float ex1 = __expf(xmv - xud1 + cm);
      float s0 = ex0;
      s0 += __shfl_xor(s0, 1); s0 += __shfl_xor(s0, 2); s0 += __shfl_xor(s0, 4);
      float s1 = ex1;
      s1 += __shfl_xor(s1, 1); s1 += __shfl_xor(s1, 2); s1 += __shfl_xor(s1, 4);
      float q0 = ex0 * __builtin_amdgcn_rcpf(s0) * evs0;
      float q1 = ex1 * __builtin_amdgcn_rcpf(s1) * evs1;
      unsigned q2u = cvt_pk_u(q0, q1);
      unsigned qj2[8];
#pragma unroll
      for (int jq = 0; jq < 8; ++jq) qj2[jq] = __shfl((int)q2u, (jq << 3) | m);

      // packed-fp16 FMA sweep over the 16 staged rows (chunk jj)
      const uint4* xbp = (const uint4*)(xsp + jj * 16);
      half2_t acc2[4];
#pragma unroll
      for (int i = 0; i < 4; ++i) acc2[i] = half2_t{(_Float16)0, (_Float16)0};
#pragma unroll
      for (int jq = 0; jq < 8; ++jq) {
        uint4 A = xbp[jq * 10];            // row jq   (160B = 10 uint4 stride)
        uint4 B = xbp[(jq + 8) * 10];      // row jq+8
        half2_t qa = u2h(dup_lo(qj2[jq]));
        half2_t qb = u2h(dup_hi(qj2[jq]));
        acc2[0] += u2h(A.x) * qa;  acc2[0] += u2h(B.x) * qb;
        acc2[1] += u2h(A.y) * qa;  acc2[1] += u2h(B.y) * qb;
        acc2[2] += u2h(A.z) * qa;  acc2[2] += u2h(B.z) * qb;
        acc2[3] += u2h(A.w) * qa;  acc2[3] += u2h(B.w) * qb;
      }
      // agg row rrow = wave*2+p: element k = m*64 + jj*8 + i, XOR-swizzled
      int rrow = wave * 2 + p;
      uint4 pk;
      pk.x = h2u(acc2[0]); pk.y = h2u(acc2[1]);
      pk.z = h2u(acc2[2]); pk.w = h2u(acc2[3]);
      int bir = m * 128 + jj * 16;
      int bo = bir ^ ((bir >> 3) & 0x70) ^ ((rrow & 7) << 4);
      *(uint4*)(aggmem + rrow * 1024 + bo) = pk;
    }

    // B2: agg visible to all waves (raw barrier — no vmcnt drain)
    asm volatile("s_waitcnt lgkmcnt(0)" ::: "memory");
    __builtin_amdgcn_s_barrier();
    asm volatile("" ::: "memory");

    // phase C: 8x64 out tile; wave w owns cols [16w,16w+16); A rows dup l&7
    f32x4 C = {0.f, 0.f, 0.f, 0.f};
#pragma unroll
    for (int ks = 0; ks < 16; ++ks) {
      int bir = ks * 64 + q4 * 16;
      int bo = bir ^ ((bir >> 3) & 0x70) ^ ((l & 7) << 4);
      half8_t afrag = *(const half8_t*)(aggmem + (l & 7) * 1024 + bo);
      half8_t bfrag = __builtin_bit_cast(half8_t, btf[ks]);
      C = __builtin_amdgcn_mfma_f32_16x16x32_f16(afrag, bfrag, C, 0, 0, 0);
    }
    if (q4 < 2) {
#pragma unroll
      for (int i = 0; i < 4; ++i)
        y[(size_t)(t * 8 + q4 * 4 + i) * 64 + col] = C[i] + bias;
    }
    asm volatile("" ::: "memory");   // pin y-stores before next alpha

    // B3: all MFMA A-reads done before next iter's agg writes (WAR)
    asm volatile("s_waitcnt lgkmcnt(0)" ::: "memory");
    __builtin_amdgcn_s_barrier();
    asm volatile("" ::: "memory");

    // rotate lin sets
    dstA = dstB; evA = evB; xmA = xmB;
    dstB = dstF; evB = evF; xmB = xmF;
  }
}

extern "C" void kernel_launch(void* const* d_in, const int* in_sizes, int n_in,
                              void* d_out, int out_size, void* d_ws, size_t ws_size,
                              hipStream_t stream) {
  const float* data      = (const float*)d_in[0];
  // d_in[1] = edge_src: structurally repeat(arange(V),16) -> implicit, unused
  const int*   edge_dst  = (const int*)d_in[2];
  const float* edge_vals = (const float*)d_in[3];
  const float* var_u     = (const float*)d_in[4];
  const float* var_c     = (const float*)d_in[5];
  const float* var_w     = (const float*)d_in[6];
  const float* var_b     = (const float*)d_in[7];
  float* y = (float*)d_out;

  char* ws = (char*)d_ws;
  char*           rowbuf = ws;                                  // 16,000,000 B
  unsigned short* Bt     = (unsigned short*)(ws + 16000000);    // 65,536 B

  hipLaunchKernelGGL(k0_prep_w, dim3(128), dim3(256), 0, stream, var_w, Bt);
  hipLaunchKernelGGL(k1_prep, dim3((NV + 255) / 256), dim3(256), 0, stream,
                     data, var_u, rowbuf);
  hipLaunchKernelGGL(k2_main, dim3(GRID), dim3(256), 0, stream,
                     rowbuf, edge_dst, edge_vals, Bt, var_c, var_b, y);
}

// Round 10
// 82.863 us; speedup vs baseline: 2.0807x; 1.1260x over previous
//
#include <hip/hip_runtime.h>

typedef _Float16 half2_t __attribute__((ext_vector_type(2)));
typedef _Float16 half8_t __attribute__((ext_vector_type(8)));
typedef __attribute__((ext_vector_type(4))) float f32x4;

#define NV 100000
#define NTILE 6250      // 16 vertices per tile
#define GRID 512        // 2 blocks/CU, persistent grid-stride
#define LDSZ 81920      // 64K X dbuf + 8K xud dbuf + 8K lin quad

#define VMWAIT(N) asm volatile("s_waitcnt vmcnt(" #N ")" ::: "memory")
#define LGKM0     asm volatile("s_waitcnt lgkmcnt(0)" ::: "memory")
#define FENCE     asm volatile("" ::: "memory")

__device__ __forceinline__ unsigned cvt_pk_u(float a, float b) {
  auto h = __builtin_amdgcn_cvt_pkrtz(a, b);
  return __builtin_bit_cast(unsigned, h);
}
__device__ __forceinline__ half2_t u2h(unsigned u) { return __builtin_bit_cast(half2_t, u); }
__device__ __forceinline__ unsigned h2u(half2_t h) { return __builtin_bit_cast(unsigned, h); }
__device__ __forceinline__ unsigned dup_lo(unsigned q) {
  return __builtin_amdgcn_perm(q, q, 0x01000100u);   // (h0,h0)
}
__device__ __forceinline__ unsigned dup_hi(unsigned q) {
  return __builtin_amdgcn_perm(q, q, 0x03020302u);   // (h1,h1)
}
// async global->LDS: lds dest = wave-uniform base + lane*16 (HW rule)
__device__ __forceinline__ void load16_to_lds(const void* g, void* s) {
  __builtin_amdgcn_global_load_lds(
      (const __attribute__((address_space(1))) unsigned int*)g,
      (__attribute__((address_space(3))) unsigned int*)s, 16, 0, 0);
}

// K0: Bt[d][k] = fp16(var_w[k*64+d]); k = m*64+c
__global__ __launch_bounds__(256) void k0_prep_w(const float* __restrict__ var_w,
                                                 unsigned short* __restrict__ Bt) {
  int t = blockIdx.x * 256 + threadIdx.x;
  if (t >= 64 * 512) return;
  int d = t >> 9, k = t & 511;
  _Float16 h = (_Float16)var_w[k * 64 + d];
  Bt[t] = __builtin_bit_cast(unsigned short, h);
}

// K1: data_h[v][64] fp16 (128B rows) ; xu_h[v][8] fp16 (16B records)
__global__ __launch_bounds__(256) void k1_prep(const float* __restrict__ data,
                                               const float* __restrict__ var_u,
                                               unsigned short* __restrict__ data_h,
                                               unsigned short* __restrict__ xu_h) {
  __shared__ float u_lds[512];
  int tid = threadIdx.x;
  u_lds[tid] = var_u[tid];
  u_lds[tid + 256] = var_u[tid + 256];
  __syncthreads();
  int v = blockIdx.x * 256 + tid;
  if (v >= NV) return;
  const float4* dp = (const float4*)(data + v * 64);
  float acc[8];
#pragma unroll
  for (int w = 0; w < 8; ++w) acc[w] = 0.f;
  uint4* ob = (uint4*)(data_h + v * 64);
#pragma unroll
  for (int q = 0; q < 8; ++q) {
    float4 a4 = dp[q * 2], b4 = dp[q * 2 + 1];
    int c0 = q * 8;
#pragma unroll
    for (int w = 0; w < 8; ++w)
      acc[w] += a4.x * u_lds[(c0 + 0) * 8 + w] + a4.y * u_lds[(c0 + 1) * 8 + w]
              + a4.z * u_lds[(c0 + 2) * 8 + w] + a4.w * u_lds[(c0 + 3) * 8 + w]
              + b4.x * u_lds[(c0 + 4) * 8 + w] + b4.y * u_lds[(c0 + 5) * 8 + w]
              + b4.z * u_lds[(c0 + 6) * 8 + w] + b4.w * u_lds[(c0 + 7) * 8 + w];
    uint4 pk;
    pk.x = cvt_pk_u(a4.x, a4.y); pk.y = cvt_pk_u(a4.z, a4.w);
    pk.z = cvt_pk_u(b4.x, b4.y); pk.w = cvt_pk_u(b4.z, b4.w);
    ob[q] = pk;
  }
  uint4 xp;
  xp.x = cvt_pk_u(acc[0], acc[1]); xp.y = cvt_pk_u(acc[2], acc[3]);
  xp.z = cvt_pk_u(acc[4], acc[5]); xp.w = cvt_pk_u(acc[6], acc[7]);
  *(uint4*)(xu_h + v * 8) = xp;
}

// K2: persistent; 16-v tiles; in-lane m-serial softmax; all gathers are DMA
// staged one tile ahead; slot parity = ITERATION COUNTER (kc) so dbufs swap.
// Sync: end-of-iteration vmcnt(4) (excludes only y-stores) + barrier.
__global__ __launch_bounds__(256, 2) void k2_main(
    const unsigned short* __restrict__ data_h,
    const unsigned short* __restrict__ xu_h,
    const int* __restrict__ edge_dst,
    const float* __restrict__ edge_vals,
    const unsigned short* __restrict__ Bt,
    const float* __restrict__ var_c,
    const float* __restrict__ var_b,
    float* __restrict__ y) {
  extern __shared__ __align__(16) char smem[];
  char* XB0  = smem;           // 2 x 32768 : X rows (256 x 128B) / agg reuse
  char* XUD0 = smem + 65536;   // 2 x 4096  : per-edge xud -> q (16B records)
  char* LIN0 = smem + 73728;   // 4 x 2048  : per-tile dst(1024B) + ev(1024B)

  int tid = threadIdx.x;
  int wave = tid >> 6;
  int l = tid & 63;
  int q4 = l >> 4;          // sweep vertex-in-wave / phase-C k-octet
  int row = l & 15;         // sweep channel-quad / phase-C A-row
  int col = row + wave * 16;
  int lsw = (l & 56) | ((l & 7) ^ q4);   // XUD slot<->edge bank swizzle

  // ---- one-time prologue ----
  uint4 btf[16];
#pragma unroll
  for (int ks = 0; ks < 16; ++ks)
    btf[ks] = *(const uint4*)(Bt + (col * 512 + ks * 32 + q4 * 8));
  float c8[8];
#pragma unroll
  for (int m = 0; m < 8; ++m) c8[m] = var_c[m];
  float bias = var_b[col];

#define LIN_DMA(SL, TS)                                                        \
  { char* lb_ = LIN0 + (SL) * 2048;                                            \
    if ((wave & 1) == 0)                                                       \
      load16_to_lds(edge_dst + (size_t)(TS) * 256 + l * 4, lb_);               \
    else                                                                       \
      load16_to_lds(edge_vals + (size_t)(TS) * 256 + l * 4, lb_ + 1024); }
#define XUD_DMA(SL, LSL)                                                       \
  { const int* ld_ = (const int*)(LIN0 + (LSL) * 2048);                        \
    int dv_ = ld_[wave * 64 + lsw];                                            \
    load16_to_lds(xu_h + (size_t)dv_ * 8, XUD0 + (SL) * 4096 + wave * 1024); }
#define X_DMA(SL, LSL)                                                         \
  { const int* ld_ = (const int*)(LIN0 + (LSL) * 2048);                        \
    _Pragma("unroll")                                                          \
    for (int s_ = 0; s_ < 8; ++s_) {                                           \
      int r_ = wave * 64 + s_ * 8 + (l >> 3);                                  \
      int dv_ = ld_[r_];                                                       \
      load16_to_lds(data_h + (size_t)dv_ * 64 + (l & 7) * 8,                   \
                    XB0 + (SL) * 32768 + (wave * 64 + s_ * 8) * 128); } }

  int t0 = blockIdx.x;
  int tG1 = (t0 + GRID < NTILE) ? t0 + GRID : t0;
  int tG2 = (t0 + 2 * GRID < NTILE) ? t0 + 2 * GRID : t0;
  FENCE;
  LIN_DMA(0, t0);
  LIN_DMA(1, tG1);
  LIN_DMA(2, tG2);
  FENCE;
  uint4 xsA = *(const uint4*)(xu_h + ((size_t)t0 * 16 + wave * 4 + q4) * 8);
  uint4 xsB = *(const uint4*)(xu_h + ((size_t)tG1 * 16 + wave * 4 + q4) * 8);
  VMWAIT(0);
  __builtin_amdgcn_s_barrier();
  FENCE;
  XUD_DMA(0, 0);
  X_DMA(0, 0);
  FENCE;
  VMWAIT(0);
  __builtin_amdgcn_s_barrier();

  int kc = 0;
  for (int t = t0; t < NTILE; t += GRID, ++kc) {
    int slc = kc & 1, lslc = kc & 3;
    int sl1 = (kc + 1) & 1, lsl1 = (kc + 1) & 3, lsl3 = (kc + 3) & 3;
    int t2c = (t + 2 * GRID < NTILE) ? t + 2 * GRID : t;
    int t3c = (t + 3 * GRID < NTILE) ? t + 3 * GRID : t;
    const char* XBt = XB0 + slc * 32768;
    char* XUDt = XUD0 + slc * 4096;
    const char* LINt = LIN0 + lslc * 2048;

    // step1: stage next tile's xud + X (9 DMAs; land during this iteration)
    FENCE;
    XUD_DMA(sl1, lsl1);
    X_DMA(sl1, lsl1);
    FENCE;

    // prepass(t): slot l holds edge (wave*64+lsw); in-lane softmax over m
    {
      uint4 xd4 = *(const uint4*)(XUDt + (wave * 64 + l) * 16);
      float evv = ((const float*)(LINt + 1024))[wave * 64 + lsw];
      half2_t xm01 = u2h(xsA.x), xm23 = u2h(xsA.y), xm45 = u2h(xsA.z), xm67 = u2h(xsA.w);
      half2_t xd01 = u2h(xd4.x), xd23 = u2h(xd4.y), xd45 = u2h(xd4.z), xd67 = u2h(xd4.w);
      float ex0 = __expf((float)xm01[0] - (float)xd01[0] + c8[0]);
      float ex1 = __expf((float)xm01[1] - (float)xd01[1] + c8[1]);
      float ex2 = __expf((float)xm23[0] - (float)xd23[0] + c8[2]);
      float ex3 = __expf((float)xm23[1] - (float)xd23[1] + c8[3]);
      float ex4 = __expf((float)xm45[0] - (float)xd45[0] + c8[4]);
      float ex5 = __expf((float)xm45[1] - (float)xd45[1] + c8[5]);
      float ex6 = __expf((float)xm67[0] - (float)xd67[0] + c8[6]);
      float ex7 = __expf((float)xm67[1] - (float)xd67[1] + c8[7]);
      float ssum = ((ex0 + ex1) + (ex2 + ex3)) + ((ex4 + ex5) + (ex6 + ex7));
      float rs = __builtin_amdgcn_rcpf(ssum) * evv;
      uint4 qq;
      qq.x = cvt_pk_u(ex0 * rs, ex1 * rs);
      qq.y = cvt_pk_u(ex2 * rs, ex3 * rs);
      qq.z = cvt_pk_u(ex4 * rs, ex5 * rs);
      qq.w = cvt_pk_u(ex6 * rs, ex7 * rs);
      *(uint4*)(XUDt + (wave * 64 + l) * 16) = qq;
    }

    // mid: future xs reg load + lin for t+3G
    uint4 xsC = *(const uint4*)(xu_h + ((size_t)t2c * 16 + wave * 4 + q4) * 8);
    FENCE;
    LIN_DMA(lsl3, t3c);
    FENCE;

    // sweep(t): lane (v=q4, ck=row); X read once; 8 m in-lane
    {
      int v = q4, ck = row;
      half2_t acc2[16];
#pragma unroll
      for (int i = 0; i < 16; ++i) acc2[i] = half2_t{(_Float16)0, (_Float16)0};
#pragma unroll
      for (int j = 0; j < 16; ++j) {
        int qslot = v * 16 + (j & 8) + ((j & 7) ^ v);
        uint4 qv = *(const uint4*)(XUDt + (wave * 64 + qslot) * 16);
        uint2 xx = *(const uint2*)(XBt + (size_t)(wave * 64 + v * 16 + j) * 128 + ck * 8);
        half2_t xlo = u2h(xx.x), xhi = u2h(xx.y);
        unsigned qu;
        qu = qv.x;
        acc2[0]  += xlo * u2h(dup_lo(qu)); acc2[1]  += xhi * u2h(dup_lo(qu));
        acc2[2]  += xlo * u2h(dup_hi(qu)); acc2[3]  += xhi * u2h(dup_hi(qu));
        qu = qv.y;
        acc2[4]  += xlo * u2h(dup_lo(qu)); acc2[5]  += xhi * u2h(dup_lo(qu));
        acc2[6]  += xlo * u2h(dup_hi(qu)); acc2[7]  += xhi * u2h(dup_hi(qu));
        qu = qv.z;
        acc2[8]  += xlo * u2h(dup_lo(qu)); acc2[9]  += xhi * u2h(dup_lo(qu));
        acc2[10] += xlo * u2h(dup_hi(qu)); acc2[11] += xhi * u2h(dup_hi(qu));
        qu = qv.w;
        acc2[12] += xlo * u2h(dup_lo(qu)); acc2[13] += xhi * u2h(dup_lo(qu));
        acc2[14] += xlo * u2h(dup_hi(qu)); acc2[15] += xhi * u2h(dup_hi(qu));
      }
      // agg[vg][m*64 + ck*4 ..+4] into consumed X region, XOR-swizzled
      int vg = wave * 4 + v;
      char* ab = (char*)XBt + vg * 2048;
#pragma unroll
      for (int m = 0; m < 8; ++m) {
        int bo = (m * 128 + ck * 8) ^ ((vg & 7) << 4);
        uint2 w2;
        w2.x = h2u(acc2[2 * m]);
        w2.y = h2u(acc2[2 * m + 1]);
        *(uint2*)(ab + bo) = w2;
      }
    }
    LGKM0;
    __builtin_amdgcn_s_barrier();   // B1: agg visible to all waves

    // phase C: 16x64 tile; wave w owns cols [16w,16w+16)
    {
      f32x4 C = {0.f, 0.f, 0.f, 0.f};
#pragma unroll
      for (int ks = 0; ks < 16; ++ks) {
        int bo = (ks * 64 + q4 * 16) ^ ((row & 7) << 4);
        half8_t af = *(const half8_t*)(XBt + row * 2048 + bo);
        C = __builtin_amdgcn_mfma_f32_16x16x32_f16(
            af, __builtin_bit_cast(half8_t, btf[ks]), C, 0, 0, 0);
      }
#pragma unroll
      for (int i = 0; i < 4; ++i)
        y[(size_t)(t * 16 + q4 * 4 + i) * 64 + col] = C[i] + bias;
    }
    LGKM0;       // phase-C agg reads retired before next iter's X DMA reuse
    VMWAIT(4);   // everything except the 4 y-stores retired
    __builtin_amdgcn_s_barrier();   // B2

    xsA = xsB; xsB = xsC;
  }
  VMWAIT(0);     // drain tail (incl. dummy prefetch DMAs) before exit
#undef LIN_DMA
#undef XUD_DMA
#undef X_DMA
}

extern "C" void kernel_launch(void* const* d_in, const int* in_sizes, int n_in,
                              void* d_out, int out_size, void* d_ws, size_t ws_size,
                              hipStream_t stream) {
  const float* data      = (const float*)d_in[0];
  // d_in[1] = edge_src: structurally repeat(arange(V),16) -> implicit, unused
  const int*   edge_dst  = (const int*)d_in[2];
  const float* edge_vals = (const float*)d_in[3];
  const float* var_u     = (const float*)d_in[4];
  const float* var_c     = (const float*)d_in[5];
  const float* var_w     = (const float*)d_in[6];
  const float* var_b     = (const float*)d_in[7];
  float* y = (float*)d_out;

  char* ws = (char*)d_ws;
  unsigned short* data_h = (unsigned short*)ws;                  // 12,800,000 B
  unsigned short* xu_h   = (unsigned short*)(ws + 12800000);     //  1,600,000 B
  unsigned short* Bt     = (unsigned short*)(ws + 14400000);     //     65,536 B

  hipFuncSetAttribute((const void*)k2_main,
                      hipFuncAttributeMaxDynamicSharedMemorySize, LDSZ);

  hipLaunchKernelGGL(k0_prep_w, dim3(128), dim3(256), 0, stream, var_w, Bt);
  hipLaunchKernelGGL(k1_prep, dim3((NV + 255) / 256), dim3(256), 0, stream,
                     data, var_u, data_h, xu_h);
  hipLaunchKernelGGL(k2_main, dim3(GRID), dim3(256), LDSZ, stream,
                     data_h, xu_h, edge_dst, edge_vals, Bt, var_c, var_b, y);
}